// Round 1
// baseline (296.573 us; speedup 1.0000x reference)
//
#include <hip/hip_runtime.h>

#define NH 16
#define DK 64
#define DM 1024
#define BB 2
#define SS 2048
#define BS (BB*SS)   // 4096 rows of x

typedef __attribute__((ext_vector_type(8))) short bf16x8;
typedef __attribute__((ext_vector_type(4))) float f32x4;

static __device__ __forceinline__ float bf2f(short s) {
  union { unsigned u; float f; } v;
  v.u = ((unsigned)(unsigned short)s) << 16;
  return v.f;
}
static __device__ __forceinline__ short f2bf(float f) {
  union { float f; unsigned u; } v; v.f = f;
  unsigned r = (v.u + 0x7fffu + ((v.u >> 16) & 1u)) >> 16;  // RTNE
  return (short)r;
}

// ---------------------------------------------------------------- convert
// xb = bf16(x); Wt[type][h][dk][d] = bf16(W*[h][d][dk]) (transposed so all
// GEMMs are the B^T pattern); Wct[n][k] = bf16(Wc[k][n]).
__global__ __launch_bounds__(256) void k_convert(
    const float* __restrict__ x,
    const float* __restrict__ Wq, const float* __restrict__ Wk,
    const float* __restrict__ Wv, const float* __restrict__ Wc,
    short* __restrict__ xb, short* __restrict__ Wt, short* __restrict__ Wct) {
  int i = blockIdx.x * 256 + threadIdx.x;
  if (i < BS*DM) { xb[i] = f2bf(x[i]); return; }
  i -= BS*DM;
  if (i < 3*NH*DM*DK) {
    int d    = i & (DM-1);
    int rest = i >> 10;
    int dk   = rest & (DK-1);
    int th   = rest >> 6;            // type*16 + h
    int type = th >> 4, h = th & (NH-1);
    const float* W = (type == 0) ? Wq : (type == 1) ? Wk : Wv;
    Wt[i] = f2bf(W[(h*DM + d)*DK + dk]);
    return;
  }
  i -= 3*NH*DM*DK;
  if (i < DM*DM) Wct[i] = f2bf(Wc[(i & (DM-1))*DM + (i >> 10)]);
}

// ---------------------------------------------------------------- QKV GEMM
// C[4096, 48*64] = xb @ Wt^T per (type,h); Q gets (acc+b)*0.125 folded in.
// Outputs Qb/Kb/Vb as [B][H][S][64] bf16.
__global__ __launch_bounds__(256) void k_qkv(
    const short* __restrict__ xb, const short* __restrict__ Wt,
    const float* __restrict__ bq, const float* __restrict__ bk,
    const float* __restrict__ bv,
    short* __restrict__ Qb, short* __restrict__ Kb, short* __restrict__ Vb) {
  __shared__ short As[64][72];
  __shared__ short Bs[64][72];
  const int tid = threadIdx.x, wave = tid >> 6, lane = tid & 63;
  const int l15 = lane & 15, quad = lane >> 4;
  const int m0 = blockIdx.x * 64;
  const int th = blockIdx.y;                  // type*16 + h
  const int type = th >> 4, h = th & 15;
  const short* Wslice = Wt + (size_t)th * DK * DM;   // [64 dk][1024 d]
  f32x4 acc[4] = {};
  for (int k0 = 0; k0 < DM; k0 += 64) {
#pragma unroll
    for (int i = 0; i < 2; i++) {
      int c = tid + i*256, row = c >> 3, c8 = (c & 7) * 8;
      *(int4*)&As[row][c8] = *(const int4*)&xb[(size_t)(m0+row)*DM + k0 + c8];
      *(int4*)&Bs[row][c8] = *(const int4*)&Wslice[(size_t)row*DM + k0 + c8];
    }
    __syncthreads();
#pragma unroll
    for (int ks = 0; ks < 64; ks += 32) {
      bf16x8 a = *(bf16x8*)&As[wave*16 + l15][ks + quad*8];
#pragma unroll
      for (int nf = 0; nf < 4; nf++) {
        bf16x8 b = *(bf16x8*)&Bs[nf*16 + l15][ks + quad*8];
        acc[nf] = __builtin_amdgcn_mfma_f32_16x16x32_bf16(a, b, acc[nf], 0, 0, 0);
      }
    }
    __syncthreads();
  }
  const float* bias = ((type == 0) ? bq : (type == 1) ? bk : bv) + h*DK;
  short* dst = (type == 0) ? Qb : (type == 1) ? Kb : Vb;
  const float scale = (type == 0) ? 0.125f : 1.0f;   // fold 1/sqrt(dk) into Q
#pragma unroll
  for (int nf = 0; nf < 4; nf++) {
    int n = nf*16 + l15;
    float bval = bias[n];
#pragma unroll
    for (int r = 0; r < 4; r++) {
      int m = m0 + wave*16 + quad*4 + r;
      int b = m >> 11, s = m & (SS-1);
      dst[(size_t)((b*NH + h)*SS + s)*DK + n] = f2bf((acc[nf][r] + bval) * scale);
    }
  }
}

// ---------------------------------------------------------------- column stats
// Z_t = sum_s exp(q_s . k_t)  (softmax is over the QUERY axis; scores bounded
// ~|2| so no max-subtraction needed). Then V'[t] = V[t]/Z_t written TRANSPOSED
// to Vt [B][H][64 dk][S] so the PV GEMM's B operand is the B^T pattern.
__global__ __launch_bounds__(256) void k_stats(
    const short* __restrict__ Qb, const short* __restrict__ Kb,
    const short* __restrict__ Vb, short* __restrict__ Vt) {
  __shared__ short Ks[64][72];
  __shared__ short Qs[64][72];
  __shared__ float red[4][64];
  __shared__ float zinv[64];
  const int tid = threadIdx.x, wave = tid >> 6, lane = tid & 63;
  const int l15 = lane & 15, quad = lane >> 4;
  const int t0 = blockIdx.x * 64;
  const int bh = blockIdx.y;
  const short* Qg = Qb + (size_t)bh * SS * DK;
  const short* Kg = Kb + (size_t)bh * SS * DK;
#pragma unroll
  for (int i = 0; i < 2; i++) {
    int c = tid + i*256, row = c >> 3, c8 = (c & 7) * 8;
    *(int4*)&Ks[row][c8] = *(const int4*)&Kg[(size_t)(t0+row)*DK + c8];
  }
  float colsum[4] = {0.f, 0.f, 0.f, 0.f};
  for (int s0 = 0; s0 < SS; s0 += 64) {
#pragma unroll
    for (int i = 0; i < 2; i++) {
      int c = tid + i*256, row = c >> 3, c8 = (c & 7) * 8;
      *(int4*)&Qs[row][c8] = *(const int4*)&Qg[(size_t)(s0+row)*DK + c8];
    }
    __syncthreads();   // also covers the one-time Ks staging on iter 0
    f32x4 sacc[4] = {};
#pragma unroll
    for (int ks = 0; ks < 64; ks += 32) {
      bf16x8 a = *(bf16x8*)&Qs[wave*16 + l15][ks + quad*8];
#pragma unroll
      for (int nf = 0; nf < 4; nf++) {
        bf16x8 b = *(bf16x8*)&Ks[nf*16 + l15][ks + quad*8];
        sacc[nf] = __builtin_amdgcn_mfma_f32_16x16x32_bf16(a, b, sacc[nf], 0, 0, 0);
      }
    }
#pragma unroll
    for (int nf = 0; nf < 4; nf++)
#pragma unroll
      for (int r = 0; r < 4; r++)
        colsum[nf] += __expf(sacc[nf][r]);   // col = t0+nf*16+l15, rows vary
    __syncthreads();
  }
  // reduce rows: across quads (shfl) then across waves (LDS)
#pragma unroll
  for (int nf = 0; nf < 4; nf++) {
    colsum[nf] += __shfl_xor(colsum[nf], 16, 64);
    colsum[nf] += __shfl_xor(colsum[nf], 32, 64);
  }
  if (lane < 16) {
#pragma unroll
    for (int nf = 0; nf < 4; nf++) red[wave][nf*16 + lane] = colsum[nf];
  }
  __syncthreads();
  if (tid < 64) {
    float z = red[0][tid] + red[1][tid] + red[2][tid] + red[3][tid];
    zinv[tid] = 1.0f / z;
  }
  __syncthreads();
  // scale + transpose V rows t0..t0+63
  const short* Vg = Vb + (size_t)bh * SS * DK;
  short* Vtg = Vt + (size_t)bh * DK * SS;
#pragma unroll
  for (int i = 0; i < 2; i++) {
    int c = tid + i*256, trow = c >> 3, c8 = (c & 7) * 8;
    union { int4 v; short s[8]; } u;
    u.v = *(const int4*)&Vg[(size_t)(t0+trow)*DK + c8];
    float sc = zinv[trow];
#pragma unroll
    for (int j = 0; j < 8; j++)
      Vtg[(size_t)(c8+j)*SS + t0 + trow] = f2bf(bf2f(u.s[j]) * sc);
  }
}

// ---------------------------------------------------------------- fused exp(QK^T) @ V'
// out[s,dk] = sum_t exp(z_st) * V'[t,dk]; P goes C-layout -> LDS -> A-layout.
__global__ __launch_bounds__(256) void k_attnpv(
    const short* __restrict__ Qb, const short* __restrict__ Kb,
    const short* __restrict__ Vt, short* __restrict__ catg) {
  __shared__ short Qs[64][72];
  __shared__ short Ks[64][72];
  __shared__ short Vs[64][72];
  __shared__ short Ps[64][72];
  const int tid = threadIdx.x, wave = tid >> 6, lane = tid & 63;
  const int l15 = lane & 15, quad = lane >> 4;
  const int s0 = blockIdx.x * 64;
  const int bh = blockIdx.y, b = bh >> 4, h = bh & 15;
  const short* Qg  = Qb + (size_t)bh * SS * DK;
  const short* Kg  = Kb + (size_t)bh * SS * DK;
  const short* Vtg = Vt + (size_t)bh * DK * SS;
#pragma unroll
  for (int i = 0; i < 2; i++) {
    int c = tid + i*256, row = c >> 3, c8 = (c & 7) * 8;
    *(int4*)&Qs[row][c8] = *(const int4*)&Qg[(size_t)(s0+row)*DK + c8];
  }
  f32x4 out[4] = {};
  for (int t0 = 0; t0 < SS; t0 += 64) {
#pragma unroll
    for (int i = 0; i < 2; i++) {
      int c = tid + i*256, row = c >> 3, c8 = (c & 7) * 8;
      *(int4*)&Ks[row][c8] = *(const int4*)&Kg[(size_t)(t0+row)*DK + c8];
      *(int4*)&Vs[row][c8] = *(const int4*)&Vtg[(size_t)row*SS + t0 + c8];
    }
    __syncthreads();
    f32x4 sacc[4] = {};
#pragma unroll
    for (int ks = 0; ks < 64; ks += 32) {
      bf16x8 a = *(bf16x8*)&Qs[wave*16 + l15][ks + quad*8];
#pragma unroll
      for (int nf = 0; nf < 4; nf++) {
        bf16x8 bfr = *(bf16x8*)&Ks[nf*16 + l15][ks + quad*8];
        sacc[nf] = __builtin_amdgcn_mfma_f32_16x16x32_bf16(a, bfr, sacc[nf], 0, 0, 0);
      }
    }
    // P: C-layout (row=quad*4+r, col=l15) -> LDS [s][t] (wave-local rows)
#pragma unroll
    for (int nf = 0; nf < 4; nf++)
#pragma unroll
      for (int r = 0; r < 4; r++)
        Ps[wave*16 + quad*4 + r][nf*16 + l15] = f2bf(__expf(sacc[nf][r]));
    __syncthreads();
#pragma unroll
    for (int tk = 0; tk < 64; tk += 32) {
      bf16x8 a = *(bf16x8*)&Ps[wave*16 + l15][tk + quad*8];
#pragma unroll
      for (int nf = 0; nf < 4; nf++) {
        bf16x8 bfr = *(bf16x8*)&Vs[nf*16 + l15][tk + quad*8];
        out[nf] = __builtin_amdgcn_mfma_f32_16x16x32_bf16(a, bfr, out[nf], 0, 0, 0);
      }
    }
    __syncthreads();
  }
  // cat[b][s][h*64+dk]
#pragma unroll
  for (int nf = 0; nf < 4; nf++)
#pragma unroll
    for (int r = 0; r < 4; r++) {
      int s  = s0 + wave*16 + quad*4 + r;
      int dk = nf*16 + l15;
      catg[(size_t)(b*SS + s)*DM + h*DK + dk] = f2bf(out[nf][r]);
    }
}

// ---------------------------------------------------------------- output proj
__global__ __launch_bounds__(256) void k_final(
    const short* __restrict__ catg, const short* __restrict__ Wct,
    const float* __restrict__ bc, float* __restrict__ out) {
  __shared__ short As[64][72];
  __shared__ short Bs[64][72];
  const int tid = threadIdx.x, wave = tid >> 6, lane = tid & 63;
  const int l15 = lane & 15, quad = lane >> 4;
  const int m0 = blockIdx.x * 64, n0 = blockIdx.y * 64;
  f32x4 acc[4] = {};
  for (int k0 = 0; k0 < DM; k0 += 64) {
#pragma unroll
    for (int i = 0; i < 2; i++) {
      int c = tid + i*256, row = c >> 3, c8 = (c & 7) * 8;
      *(int4*)&As[row][c8] = *(const int4*)&catg[(size_t)(m0+row)*DM + k0 + c8];
      *(int4*)&Bs[row][c8] = *(const int4*)&Wct[(size_t)(n0+row)*DM + k0 + c8];
    }
    __syncthreads();
#pragma unroll
    for (int ks = 0; ks < 64; ks += 32) {
      bf16x8 a = *(bf16x8*)&As[wave*16 + l15][ks + quad*8];
#pragma unroll
      for (int nf = 0; nf < 4; nf++) {
        bf16x8 b = *(bf16x8*)&Bs[nf*16 + l15][ks + quad*8];
        acc[nf] = __builtin_amdgcn_mfma_f32_16x16x32_bf16(a, b, acc[nf], 0, 0, 0);
      }
    }
    __syncthreads();
  }
#pragma unroll
  for (int nf = 0; nf < 4; nf++) {
    int n = n0 + nf*16 + l15;
    float bval = bc[n];
#pragma unroll
    for (int r = 0; r < 4; r++) {
      int m = m0 + wave*16 + quad*4 + r;
      out[(size_t)m*DM + n] = acc[nf][r] + bval;
    }
  }
}

extern "C" void kernel_launch(void* const* d_in, const int* in_sizes, int n_in,
                              void* d_out, int out_size, void* d_ws, size_t ws_size,
                              hipStream_t stream) {
  (void)in_sizes; (void)n_in; (void)out_size; (void)ws_size;
  const float* x  = (const float*)d_in[0];
  const float* Wq = (const float*)d_in[1];
  const float* bq = (const float*)d_in[2];
  const float* Wk = (const float*)d_in[3];
  const float* bk = (const float*)d_in[4];
  const float* Wv = (const float*)d_in[5];
  const float* bv = (const float*)d_in[6];
  const float* Wc = (const float*)d_in[7];
  const float* bc = (const float*)d_in[8];
  float* out = (float*)d_out;

  // workspace layout (~56 MB total)
  char* ws = (char*)d_ws;
  size_t o = 0;
  short* xb  = (short*)(ws + o); o += (size_t)BS*DM*2;         // 8 MB
  short* Wt  = (short*)(ws + o); o += (size_t)3*NH*DK*DM*2;    // 6 MB
  short* Wct = (short*)(ws + o); o += (size_t)DM*DM*2;         // 2 MB
  short* Qb  = (short*)(ws + o); o += (size_t)BB*NH*SS*DK*2;   // 8 MB
  short* Kb  = (short*)(ws + o); o += (size_t)BB*NH*SS*DK*2;   // 8 MB
  short* Vb  = (short*)(ws + o); o += (size_t)BB*NH*SS*DK*2;   // 8 MB
  short* Vt  = (short*)(ws + o); o += (size_t)BB*NH*DK*SS*2;   // 8 MB
  short* cat = (short*)(ws + o); o += (size_t)BS*DM*2;         // 8 MB

  const int total = BS*DM + 3*NH*DM*DK + DM*DM;   // 8,388,608
  k_convert<<<dim3((total + 255)/256), 256, 0, stream>>>(x, Wq, Wk, Wv, Wc, xb, Wt, Wct);
  k_qkv   <<<dim3(BS/64, 48),      256, 0, stream>>>(xb, Wt, bq, bk, bv, Qb, Kb, Vb);
  k_stats <<<dim3(SS/64, BB*NH),   256, 0, stream>>>(Qb, Kb, Vb, Vt);
  k_attnpv<<<dim3(SS/64, BB*NH),   256, 0, stream>>>(Qb, Kb, Vt, cat);
  k_final <<<dim3(BS/64, DM/64),   256, 0, stream>>>(cat, Wct, bc, out);
}

// Round 2
// 256.200 us; speedup vs baseline: 1.1576x; 1.1576x over previous
//
#include <hip/hip_runtime.h>

#define NH 16
#define DK 64
#define DM 1024
#define BB 2
#define SS 2048
#define BS (BB*SS)   // 4096 rows of x

typedef __attribute__((ext_vector_type(8))) short bf16x8;
typedef __attribute__((ext_vector_type(4))) short short4v;
typedef __attribute__((ext_vector_type(4))) float f32x4;

#define MFMA16 __builtin_amdgcn_mfma_f32_16x16x32_bf16

static __device__ __forceinline__ float bf2f(short s) {
  union { unsigned u; float f; } v;
  v.u = ((unsigned)(unsigned short)s) << 16;
  return v.f;
}
static __device__ __forceinline__ short f2bf(float f) {
  union { float f; unsigned u; } v; v.f = f;
  unsigned r = (v.u + 0x7fffu + ((v.u >> 16) & 1u)) >> 16;  // RTNE
  return (short)r;
}

// Swizzled LDS tile: rows of C16*16 bytes, 16B chunk index XORed with row
// (lets global_load_lds stage with its lane-contiguous dest while fragment
// b128 reads stay bank-conflict-minimal). Offset in shorts.
template<int C16>
static __device__ __forceinline__ int soff(int row, int chunk) {
  return row*(C16*8) + ((chunk ^ (row & (C16-1))) << 3);
}

// Stage an R-row tile (C16 16B-chunks per row) from global rows of stride
// gstride (shorts) via async global->LDS DMA. Swizzle folded into gaddr.
template<int C16, int R>
static __device__ __forceinline__ void stage(const short* __restrict__ g, int gstride,
                                             short* l, int wave, int lane) {
  const int rloc = lane / C16;
  const int c    = lane % C16;
#pragma unroll
  for (int rr = 0; rr < R; rr += 4*(64/C16)) {
    int rbase = rr + wave*(64/C16);          // wave-uniform
    int row   = rbase + rloc;
    int cg    = c ^ (row & (C16-1));
    __builtin_amdgcn_global_load_lds(
        (const __attribute__((address_space(1))) void*)(g + (size_t)row*gstride + cg*8),
        (__attribute__((address_space(3))) void*)(l + rbase*(C16*8)),
        16, 0, 0);
  }
}

// ---------------------------------------------------------------- convert
__global__ __launch_bounds__(256) void k_convert(
    const float* __restrict__ x,
    const float* __restrict__ Wq, const float* __restrict__ Wk,
    const float* __restrict__ Wv, const float* __restrict__ Wc,
    short* __restrict__ xb, short* __restrict__ Wt, short* __restrict__ Wct) {
  int i = blockIdx.x * 256 + threadIdx.x;
  if (i < BS*DM) { xb[i] = f2bf(x[i]); return; }
  i -= BS*DM;
  if (i < 3*NH*DM*DK) {
    int d    = i & (DM-1);
    int rest = i >> 10;
    int dk   = rest & (DK-1);
    int th   = rest >> 6;            // type*16 + h
    int type = th >> 4, h = th & (NH-1);
    const float* W = (type == 0) ? Wq : (type == 1) ? Wk : Wv;
    Wt[i] = f2bf(W[(h*DM + d)*DK + dk]);
    return;
  }
  i -= 3*NH*DM*DK;
  if (i < DM*DM) Wct[i] = f2bf(Wc[(i & (DM-1))*DM + (i >> 10)]);
}

// ---------------------------------------------------------------- QKV GEMM
// C[4096,3072] = xb @ Wt^T, one fused GEMM (m97 structure: 128x128 tile, BK=64).
__global__ __launch_bounds__(256) void k_qkv(
    const short* __restrict__ xb, const short* __restrict__ Wt,
    const float* __restrict__ bq, const float* __restrict__ bk,
    const float* __restrict__ bv,
    short* __restrict__ Qb, short* __restrict__ Kb, short* __restrict__ Vb) {
  __shared__ __align__(16) short As[128*64];
  __shared__ __align__(16) short Bs[128*64];
  const int tid = threadIdx.x, wave = tid >> 6, lane = tid & 63;
  const int l15 = lane & 15, quad = lane >> 4;
  const int m0 = blockIdx.x * 128, n0 = blockIdx.y * 128;
  const int mw = (wave & 1) * 64, nw = (wave >> 1) * 64;
  f32x4 acc[4][4] = {};
  for (int k0 = 0; k0 < DM; k0 += 64) {
    stage<8,128>(xb + (size_t)m0*DM + k0, DM, As, wave, lane);
    stage<8,128>(Wt + (size_t)n0*DM + k0, DM, Bs, wave, lane);
    __syncthreads();
#pragma unroll
    for (int ks = 0; ks < 2; ks++) {
      bf16x8 a[4], b[4];
#pragma unroll
      for (int g = 0; g < 4; g++)  a[g]  = *(const bf16x8*)&As[soff<8>(mw + g*16 + l15,  ks*4 + quad)];
#pragma unroll
      for (int nf = 0; nf < 4; nf++) b[nf] = *(const bf16x8*)&Bs[soff<8>(nw + nf*16 + l15, ks*4 + quad)];
#pragma unroll
      for (int g = 0; g < 4; g++)
#pragma unroll
        for (int nf = 0; nf < 4; nf++)
          acc[g][nf] = MFMA16(a[g], b[nf], acc[g][nf], 0, 0, 0);
    }
    __syncthreads();
  }
  const int n_base = n0 + nw;          // 64-aligned -> th constant per wave
  const int th = n_base >> 6;
  const int type = th >> 4, h = th & 15;
  short* dst = (type == 0) ? Qb : (type == 1) ? Kb : Vb;
  const float* bias = ((type == 0) ? bq : (type == 1) ? bk : bv) + h*DK;
  const float scale = (type == 0) ? 0.125f : 1.0f;   // fold 1/sqrt(dk) into Q
#pragma unroll
  for (int nf = 0; nf < 4; nf++) {
    int dk = nf*16 + l15;
    float bval = bias[dk];
#pragma unroll
    for (int g = 0; g < 4; g++)
#pragma unroll
      for (int r = 0; r < 4; r++) {
        int m = m0 + mw + g*16 + quad*4 + r;
        int b_ = m >> 11, s = m & (SS-1);
        dst[(size_t)((b_*NH + h)*SS + s)*DK + dk] = f2bf((acc[g][nf][r] + bval) * scale);
      }
  }
}

// ---------------------------------------------------------------- column stats
// Z_t = sum_s exp(q_s.k_t); V'[t] = V[t]/Z_t written transposed to Vt[bh][dk][S].
// Block: 128 t columns (K-tile resident), loop s over 2048 in 128-chunks.
__global__ __launch_bounds__(256) void k_stats(
    const short* __restrict__ Qb, const short* __restrict__ Kb,
    const short* __restrict__ Vb, short* __restrict__ Vt) {
  __shared__ __align__(16) short Ks[128*64];
  __shared__ __align__(16) short Qs[128*64];   // reused as Vtile (64x128, C16=16)
  __shared__ float red[4][64];
  __shared__ float zinv[128];
  const int tid = threadIdx.x, wave = tid >> 6, lane = tid & 63;
  const int l15 = lane & 15, quad = lane >> 4;
  const int t0 = blockIdx.x * 128;
  const int bh = blockIdx.y;
  const short* Qg = Qb + (size_t)bh * SS * DK;
  const short* Kg = Kb + (size_t)bh * SS * DK;
  const int mw = (wave & 1) * 64, nw = (wave >> 1) * 64;
  stage<8,128>(Kg + (size_t)t0*DK, DK, Ks, wave, lane);
  float csum[4] = {0.f, 0.f, 0.f, 0.f};
  for (int s0 = 0; s0 < SS; s0 += 128) {
    stage<8,128>(Qg + (size_t)s0*DK, DK, Qs, wave, lane);
    __syncthreads();
    f32x4 acc[4][4] = {};
#pragma unroll
    for (int ks = 0; ks < 2; ks++) {
      bf16x8 a[4], b[4];
#pragma unroll
      for (int g = 0; g < 4; g++)  a[g]  = *(const bf16x8*)&Qs[soff<8>(mw + g*16 + l15,  ks*4 + quad)];
#pragma unroll
      for (int nf = 0; nf < 4; nf++) b[nf] = *(const bf16x8*)&Ks[soff<8>(nw + nf*16 + l15, ks*4 + quad)];
#pragma unroll
      for (int g = 0; g < 4; g++)
#pragma unroll
        for (int nf = 0; nf < 4; nf++)
          acc[g][nf] = MFMA16(a[g], b[nf], acc[g][nf], 0, 0, 0);
    }
#pragma unroll
    for (int nf = 0; nf < 4; nf++)
#pragma unroll
      for (int g = 0; g < 4; g++)
#pragma unroll
        for (int r = 0; r < 4; r++)
          csum[nf] += __expf(acc[g][nf][r]);
    __syncthreads();
  }
#pragma unroll
  for (int nf = 0; nf < 4; nf++) {
    csum[nf] += __shfl_xor(csum[nf], 16, 64);
    csum[nf] += __shfl_xor(csum[nf], 32, 64);
  }
  if (lane < 16) {
#pragma unroll
    for (int nf = 0; nf < 4; nf++) red[wave][nf*16 + lane] = csum[nf];
  }
  __syncthreads();
  if (tid < 128) {
    int half = tid >> 6, c = tid & 63;
    zinv[tid] = 1.0f / (red[half*2][c] + red[half*2 + 1][c]);
  }
  __syncthreads();
  // scale V rows t0..t0+127 into transposed swizzled LDS tile, then coalesced out
  short* Vtile = Qs;
  const short* Vg = Vb + (size_t)bh * SS * DK;
#pragma unroll
  for (int it = 0; it < 4; it++) {
    int c = tid + it*256;
    int trow = c >> 3, c8 = (c & 7) * 8;
    union { int4 v; short s[8]; } u;
    u.v = *(const int4*)&Vg[(size_t)(t0 + trow)*DK + c8];
    float sc = zinv[trow];
#pragma unroll
    for (int j = 0; j < 8; j++) {
      int dk = c8 + j;
      Vtile[dk*128 + (((trow >> 3) ^ (dk & 15)) << 3) + (trow & 7)] = f2bf(bf2f(u.s[j]) * sc);
    }
  }
  __syncthreads();
  short* Vtg = Vt + (size_t)bh * DK * SS;
#pragma unroll
  for (int it = 0; it < 4; it++) {
    int row = it*16 + (tid >> 4), cc = tid & 15;
    *(int4*)&Vtg[(size_t)row*SS + t0 + cc*8] = *(const int4*)&Vtile[soff<16>(row, cc)];
  }
}

// ---------------------------------------------------------------- fused exp(QK^T) @ V'
// 128 queries/block, t-step 64. Computes S^T = K.Q^T so P-fragments pack into
// b64 LDS writes (4 consecutive t per lane); PV reads P in A-layout via b128.
__global__ __launch_bounds__(256) void k_attnpv(
    const short* __restrict__ Qb, const short* __restrict__ Kb,
    const short* __restrict__ Vt, short* __restrict__ catg) {
  __shared__ __align__(16) short Qs[128*64];
  __shared__ __align__(16) short Ks[64*64];
  __shared__ __align__(16) short Vs[64*64];
  __shared__ __align__(16) short Ps[128*64];
  const int tid = threadIdx.x, wave = tid >> 6, lane = tid & 63;
  const int l15 = lane & 15, quad = lane >> 4;
  const int s0 = blockIdx.x * 128;
  const int bh = blockIdx.y, b = bh >> 4, h = bh & 15;
  const short* Qg  = Qb + (size_t)bh * SS * DK;
  const short* Kg  = Kb + (size_t)bh * SS * DK;
  const short* Vtg = Vt + (size_t)bh * DK * SS;
  stage<8,128>(Qg + (size_t)s0*DK, DK, Qs, wave, lane);
  const int qn = wave * 32;                               // QK: s-col base
  const int pm = (wave & 1) * 64, pn = (wave >> 1) * 32;  // PV: s-row / dk base
  f32x4 out[4][2] = {};
  for (int t0 = 0; t0 < SS; t0 += 64) {
    stage<8,64>(Kg + (size_t)t0*DK, DK, Ks, wave, lane);
    stage<8,64>(Vtg + t0, SS, Vs, wave, lane);
    __syncthreads();
    // S^T[t][s]: A = K rows (t), B = Q rows (s)
    f32x4 sacc[4][2] = {};
#pragma unroll
    for (int ks = 0; ks < 2; ks++) {
      bf16x8 a[4], bq2[2];
#pragma unroll
      for (int g = 0; g < 4; g++)  a[g]   = *(const bf16x8*)&Ks[soff<8>(g*16 + l15,       ks*4 + quad)];
#pragma unroll
      for (int nf = 0; nf < 2; nf++) bq2[nf] = *(const bf16x8*)&Qs[soff<8>(qn + nf*16 + l15, ks*4 + quad)];
#pragma unroll
      for (int g = 0; g < 4; g++)
#pragma unroll
        for (int nf = 0; nf < 2; nf++)
          sacc[g][nf] = MFMA16(a[g], bq2[nf], sacc[g][nf], 0, 0, 0);
    }
    // exp + pack: thread holds 4 consecutive t at fixed s -> one b64 write each
#pragma unroll
    for (int g = 0; g < 4; g++)
#pragma unroll
      for (int nf = 0; nf < 2; nf++) {
        int srow = qn + nf*16 + l15;
        short4v p4;
        p4[0] = f2bf(__expf(sacc[g][nf][0]));
        p4[1] = f2bf(__expf(sacc[g][nf][1]));
        p4[2] = f2bf(__expf(sacc[g][nf][2]));
        p4[3] = f2bf(__expf(sacc[g][nf][3]));
        int chunk = (2*g + (quad >> 1)) ^ (srow & 7);
        *(short4v*)&Ps[srow*64 + (chunk << 3) + ((quad & 1) << 2)] = p4;
      }
    __syncthreads();
    // out[s][dk] += P @ V'^T : A = P rows (s), B = Vt rows (dk)
#pragma unroll
    for (int ks = 0; ks < 2; ks++) {
      bf16x8 pa[4], vb2[2];
#pragma unroll
      for (int g = 0; g < 4; g++)  pa[g]   = *(const bf16x8*)&Ps[soff<8>(pm + g*16 + l15,  ks*4 + quad)];
#pragma unroll
      for (int nf = 0; nf < 2; nf++) vb2[nf] = *(const bf16x8*)&Vs[soff<8>(pn + nf*16 + l15, ks*4 + quad)];
#pragma unroll
      for (int g = 0; g < 4; g++)
#pragma unroll
        for (int nf = 0; nf < 2; nf++)
          out[g][nf] = MFMA16(pa[g], vb2[nf], out[g][nf], 0, 0, 0);
    }
    __syncthreads();
  }
#pragma unroll
  for (int g = 0; g < 4; g++)
#pragma unroll
    for (int nf = 0; nf < 2; nf++)
#pragma unroll
      for (int r = 0; r < 4; r++) {
        int s  = s0 + pm + g*16 + quad*4 + r;
        int dk = pn + nf*16 + l15;
        catg[(size_t)(b*SS + s)*DM + h*DK + dk] = f2bf(out[g][nf][r]);
      }
}

// ---------------------------------------------------------------- output proj
__global__ __launch_bounds__(256) void k_final(
    const short* __restrict__ catg, const short* __restrict__ Wct,
    const float* __restrict__ bc, float* __restrict__ out) {
  __shared__ __align__(16) short As[128*64];
  __shared__ __align__(16) short Bs[128*64];
  const int tid = threadIdx.x, wave = tid >> 6, lane = tid & 63;
  const int l15 = lane & 15, quad = lane >> 4;
  const int m0 = blockIdx.x * 128, n0 = blockIdx.y * 128;
  const int mw = (wave & 1) * 64, nw = (wave >> 1) * 64;
  f32x4 acc[4][4] = {};
  for (int k0 = 0; k0 < DM; k0 += 64) {
    stage<8,128>(catg + (size_t)m0*DM + k0, DM, As, wave, lane);
    stage<8,128>(Wct  + (size_t)n0*DM + k0, DM, Bs, wave, lane);
    __syncthreads();
#pragma unroll
    for (int ks = 0; ks < 2; ks++) {
      bf16x8 a[4], b[4];
#pragma unroll
      for (int g = 0; g < 4; g++)  a[g]  = *(const bf16x8*)&As[soff<8>(mw + g*16 + l15,  ks*4 + quad)];
#pragma unroll
      for (int nf = 0; nf < 4; nf++) b[nf] = *(const bf16x8*)&Bs[soff<8>(nw + nf*16 + l15, ks*4 + quad)];
#pragma unroll
      for (int g = 0; g < 4; g++)
#pragma unroll
        for (int nf = 0; nf < 4; nf++)
          acc[g][nf] = MFMA16(a[g], b[nf], acc[g][nf], 0, 0, 0);
    }
    __syncthreads();
  }
#pragma unroll
  for (int nf = 0; nf < 4; nf++) {
    int n = n0 + nw + nf*16 + l15;
    float bval = bc[n];
#pragma unroll
    for (int g = 0; g < 4; g++)
#pragma unroll
      for (int r = 0; r < 4; r++) {
        int m = m0 + mw + g*16 + quad*4 + r;
        out[(size_t)m*DM + n] = acc[g][nf][r] + bval;
      }
  }
}

extern "C" void kernel_launch(void* const* d_in, const int* in_sizes, int n_in,
                              void* d_out, int out_size, void* d_ws, size_t ws_size,
                              hipStream_t stream) {
  (void)in_sizes; (void)n_in; (void)out_size; (void)ws_size;
  const float* x  = (const float*)d_in[0];
  const float* Wq = (const float*)d_in[1];
  const float* bq = (const float*)d_in[2];
  const float* Wk = (const float*)d_in[3];
  const float* bk = (const float*)d_in[4];
  const float* Wv = (const float*)d_in[5];
  const float* bv = (const float*)d_in[6];
  const float* Wc = (const float*)d_in[7];
  const float* bc = (const float*)d_in[8];
  float* out = (float*)d_out;

  char* ws = (char*)d_ws;
  size_t o = 0;
  short* xb  = (short*)(ws + o); o += (size_t)BS*DM*2;
  short* Wt  = (short*)(ws + o); o += (size_t)3*NH*DK*DM*2;
  short* Wct = (short*)(ws + o); o += (size_t)DM*DM*2;
  short* Qb  = (short*)(ws + o); o += (size_t)BB*NH*SS*DK*2;
  short* Kb  = (short*)(ws + o); o += (size_t)BB*NH*SS*DK*2;
  short* Vb  = (short*)(ws + o); o += (size_t)BB*NH*SS*DK*2;
  short* Vt  = (short*)(ws + o); o += (size_t)BB*NH*DK*SS*2;
  short* cat = (short*)(ws + o); o += (size_t)BS*DM*2;

  const int total = BS*DM + 3*NH*DM*DK + DM*DM;
  k_convert<<<dim3((total + 255)/256), 256, 0, stream>>>(x, Wq, Wk, Wv, Wc, xb, Wt, Wct);
  k_qkv   <<<dim3(BS/128, 3*NH*DK/128), 256, 0, stream>>>(xb, Wt, bq, bk, bv, Qb, Kb, Vb);
  k_stats <<<dim3(SS/128, BB*NH),       256, 0, stream>>>(Qb, Kb, Vb, Vt);
  k_attnpv<<<dim3(SS/128, BB*NH),       256, 0, stream>>>(Qb, Kb, Vt, cat);
  k_final <<<dim3(BS/128, DM/128),      256, 0, stream>>>(cat, Wct, bc, out);
}

// Round 3
// 239.451 us; speedup vs baseline: 1.2386x; 1.0699x over previous
//
#include <hip/hip_runtime.h>

#define NH 16
#define DK 64
#define DM 1024
#define BB 2
#define SS 2048
#define BS (BB*SS)   // 4096 rows of x

typedef __attribute__((ext_vector_type(8))) short bf16x8;
typedef __attribute__((ext_vector_type(4))) short short4v;
typedef __attribute__((ext_vector_type(4))) float f32x4;

#define MFMA16 __builtin_amdgcn_mfma_f32_16x16x32_bf16

static __device__ __forceinline__ float bf2f(short s) {
  union { unsigned u; float f; } v;
  v.u = ((unsigned)(unsigned short)s) << 16;
  return v.f;
}
static __device__ __forceinline__ short f2bf(float f) {
  union { float f; unsigned u; } v; v.f = f;
  unsigned r = (v.u + 0x7fffu + ((v.u >> 16) & 1u)) >> 16;  // RTNE
  return (short)r;
}

// Swizzled LDS tile: rows of C16*16 bytes, 16B chunk index XORed with row.
template<int C16>
static __device__ __forceinline__ int soff(int row, int chunk) {
  return row*(C16*8) + ((chunk ^ (row & (C16-1))) << 3);
}

// Async global->LDS staging, 16B/lane, swizzle folded into the global address.
template<int C16, int R>
static __device__ __forceinline__ void stage(const short* __restrict__ g, int gstride,
                                             short* l, int wave, int lane) {
  const int rloc = lane / C16;
  const int c    = lane % C16;
#pragma unroll
  for (int rr = 0; rr < R; rr += 4*(64/C16)) {
    int rbase = rr + wave*(64/C16);          // wave-uniform
    int row   = rbase + rloc;
    int cg    = c ^ (row & (C16-1));
    __builtin_amdgcn_global_load_lds(
        (const __attribute__((address_space(1))) void*)(g + (size_t)row*gstride + cg*8),
        (__attribute__((address_space(3))) void*)(l + rbase*(C16*8)),
        16, 0, 0);
  }
}

// ---------------------------------------------------------------- convert
// Coalesced everywhere: x elementwise; W*/Wc via 64x64 LDS-tiled transpose.
__global__ __launch_bounds__(256) void k_convert(
    const float* __restrict__ x,
    const float* __restrict__ Wq, const float* __restrict__ Wk,
    const float* __restrict__ Wv, const float* __restrict__ Wc,
    short* __restrict__ xb, short* __restrict__ Wt, short* __restrict__ Wct) {
  __shared__ float T[64][65];
  const int tid = threadIdx.x;
  int bx = blockIdx.x;
  const int XB = BS*DM/(256*4);                 // 4096 blocks: x -> xb
  if (bx < XB) {
    int i = (bx*256 + tid)*4;
    float4 v = *(const float4*)&x[i];
    short4v o; o[0]=f2bf(v.x); o[1]=f2bf(v.y); o[2]=f2bf(v.z); o[3]=f2bf(v.w);
    *(short4v*)&xb[i] = o;
    return;
  }
  bx -= XB;
  if (bx < 48*16) {                             // Wq/Wk/Wv -> Wt[th][dk][d]
    int th = bx >> 4, d0 = (bx & 15) * 64;
    int type = th >> 4, h = th & 15;
    const float* W = ((type == 0) ? Wq : (type == 1) ? Wk : Wv)
                     + (size_t)h*DM*DK + (size_t)d0*DK;
#pragma unroll
    for (int p = 0; p < 4; p++) {
      int dr = p*16 + (tid >> 4), dkc = (tid & 15) * 4;
      float4 v = *(const float4*)&W[(size_t)dr*DK + dkc];
      T[dkc+0][dr]=v.x; T[dkc+1][dr]=v.y; T[dkc+2][dr]=v.z; T[dkc+3][dr]=v.w;
    }
    __syncthreads();
#pragma unroll
    for (int e = 0; e < 2; e++) {
      int c = tid*2 + e, dk = c >> 3, dd = (c & 7) * 8;
      union { short s[8]; int4 v; } u;
#pragma unroll
      for (int j = 0; j < 8; j++) u.s[j] = f2bf(T[dk][dd+j]);
      *(int4*)&Wt[((size_t)th*DK + dk)*DM + d0 + dd] = u.v;
    }
    return;
  }
  bx -= 48*16;                                  // Wc -> Wct[n][k]
  int n0 = (bx >> 4) * 64, k0 = (bx & 15) * 64;
#pragma unroll
  for (int p = 0; p < 4; p++) {
    int kr = p*16 + (tid >> 4), nc = (tid & 15) * 4;
    float4 v = *(const float4*)&Wc[(size_t)(k0+kr)*DM + n0 + nc];
    T[nc+0][kr]=v.x; T[nc+1][kr]=v.y; T[nc+2][kr]=v.z; T[nc+3][kr]=v.w;
  }
  __syncthreads();
#pragma unroll
  for (int e = 0; e < 2; e++) {
    int c = tid*2 + e, n = c >> 3, kk = (c & 7) * 8;
    union { short s[8]; int4 v; } u;
#pragma unroll
    for (int j = 0; j < 8; j++) u.s[j] = f2bf(T[n][kk+j]);
    *(int4*)&Wct[(size_t)(n0+n)*DM + k0 + kk] = u.v;
  }
}

// ---------------------------------------------------------------- QKV GEMM
__global__ __launch_bounds__(256) void k_qkv(
    const short* __restrict__ xb, const short* __restrict__ Wt,
    const float* __restrict__ bq, const float* __restrict__ bk,
    const float* __restrict__ bv,
    short* __restrict__ Qb, short* __restrict__ Kb, short* __restrict__ Vb) {
  __shared__ __align__(16) short As[128*64];
  __shared__ __align__(16) short Bs[128*64];
  const int tid = threadIdx.x, wave = tid >> 6, lane = tid & 63;
  const int l15 = lane & 15, quad = lane >> 4;
  const int m0 = blockIdx.x * 128, n0 = blockIdx.y * 128;
  const int mw = (wave & 1) * 64, nw = (wave >> 1) * 64;
  f32x4 acc[4][4] = {};
  for (int k0 = 0; k0 < DM; k0 += 64) {
    stage<8,128>(xb + (size_t)m0*DM + k0, DM, As, wave, lane);
    stage<8,128>(Wt + (size_t)n0*DM + k0, DM, Bs, wave, lane);
    __syncthreads();
#pragma unroll
    for (int ks = 0; ks < 2; ks++) {
      bf16x8 a[4], b[4];
#pragma unroll
      for (int g = 0; g < 4; g++)  a[g]  = *(const bf16x8*)&As[soff<8>(mw + g*16 + l15,  ks*4 + quad)];
#pragma unroll
      for (int nf = 0; nf < 4; nf++) b[nf] = *(const bf16x8*)&Bs[soff<8>(nw + nf*16 + l15, ks*4 + quad)];
#pragma unroll
      for (int g = 0; g < 4; g++)
#pragma unroll
        for (int nf = 0; nf < 4; nf++)
          acc[g][nf] = MFMA16(a[g], b[nf], acc[g][nf], 0, 0, 0);
    }
    __syncthreads();
  }
  const int th = (n0 + nw) >> 6;
  const int type = th >> 4, h = th & 15;
  short* dst = (type == 0) ? Qb : (type == 1) ? Kb : Vb;
  const float* bias = ((type == 0) ? bq : (type == 1) ? bk : bv) + h*DK;
  const float scale = (type == 0) ? 0.125f : 1.0f;
#pragma unroll
  for (int nf = 0; nf < 4; nf++) {
    int dk = nf*16 + l15;
    float bval = bias[dk];
#pragma unroll
    for (int g = 0; g < 4; g++)
#pragma unroll
      for (int r = 0; r < 4; r++) {
        int m = m0 + mw + g*16 + quad*4 + r;
        int b_ = m >> 11, s = m & (SS-1);
        dst[(size_t)((b_*NH + h)*SS + s)*DK + dk] = f2bf((acc[g][nf][r] + bval) * scale);
      }
  }
}

// ---------------------------------------------------------------- column stats
__global__ __launch_bounds__(256) void k_stats(
    const short* __restrict__ Qb, const short* __restrict__ Kb,
    const short* __restrict__ Vb, short* __restrict__ Vt) {
  __shared__ __align__(16) short Ks[128*64];
  __shared__ __align__(16) short Qs[128*64];   // reused as Vtile (64x128)
  __shared__ float red[4][64];
  __shared__ float zinv[128];
  const int tid = threadIdx.x, wave = tid >> 6, lane = tid & 63;
  const int l15 = lane & 15, quad = lane >> 4;
  const int t0 = blockIdx.x * 128;
  const int bh = blockIdx.y;
  const short* Qg = Qb + (size_t)bh * SS * DK;
  const short* Kg = Kb + (size_t)bh * SS * DK;
  const int mw = (wave & 1) * 64, nw = (wave >> 1) * 64;
  stage<8,128>(Kg + (size_t)t0*DK, DK, Ks, wave, lane);
  __syncthreads();
  bf16x8 kf[2][4];                              // K-tile is loop-invariant: hoist
#pragma unroll
  for (int ks = 0; ks < 2; ks++)
#pragma unroll
    for (int nf = 0; nf < 4; nf++)
      kf[ks][nf] = *(const bf16x8*)&Ks[soff<8>(nw + nf*16 + l15, ks*4 + quad)];
  float csum[4] = {0.f, 0.f, 0.f, 0.f};
  for (int s0 = 0; s0 < SS; s0 += 128) {
    stage<8,128>(Qg + (size_t)s0*DK, DK, Qs, wave, lane);
    __syncthreads();
    f32x4 acc[4][4] = {};
#pragma unroll
    for (int ks = 0; ks < 2; ks++) {
      bf16x8 a[4];
#pragma unroll
      for (int g = 0; g < 4; g++) a[g] = *(const bf16x8*)&Qs[soff<8>(mw + g*16 + l15, ks*4 + quad)];
#pragma unroll
      for (int g = 0; g < 4; g++)
#pragma unroll
        for (int nf = 0; nf < 4; nf++)
          acc[g][nf] = MFMA16(a[g], kf[ks][nf], acc[g][nf], 0, 0, 0);
    }
#pragma unroll
    for (int nf = 0; nf < 4; nf++)
#pragma unroll
      for (int g = 0; g < 4; g++)
#pragma unroll
        for (int r = 0; r < 4; r++)
          csum[nf] += __expf(acc[g][nf][r]);
    __syncthreads();
  }
#pragma unroll
  for (int nf = 0; nf < 4; nf++) {
    csum[nf] += __shfl_xor(csum[nf], 16, 64);
    csum[nf] += __shfl_xor(csum[nf], 32, 64);
  }
  if (lane < 16) {
#pragma unroll
    for (int nf = 0; nf < 4; nf++) red[wave][nf*16 + lane] = csum[nf];
  }
  __syncthreads();
  if (tid < 128) {
    int half = tid >> 6, c = tid & 63;
    zinv[tid] = 1.0f / (red[half*2][c] + red[half*2 + 1][c]);
  }
  __syncthreads();
  short* Vtile = Qs;
  const short* Vg = Vb + (size_t)bh * SS * DK;
#pragma unroll
  for (int it = 0; it < 4; it++) {
    int c = tid + it*256;
    int trow = c >> 3, c8 = (c & 7) * 8;
    union { int4 v; short s[8]; } u;
    u.v = *(const int4*)&Vg[(size_t)(t0 + trow)*DK + c8];
    float sc = zinv[trow];
#pragma unroll
    for (int j = 0; j < 8; j++) {
      int dk = c8 + j;
      Vtile[dk*128 + (((trow >> 3) ^ (dk & 15)) << 3) + (trow & 7)] = f2bf(bf2f(u.s[j]) * sc);
    }
  }
  __syncthreads();
  short* Vtg = Vt + (size_t)bh * DK * SS;
#pragma unroll
  for (int it = 0; it < 4; it++) {
    int row = it*16 + (tid >> 4), cc = tid & 15;
    *(int4*)&Vtg[(size_t)row*SS + t0 + cc*8] = *(const int4*)&Vtile[soff<16>(row, cc)];
  }
}

// ---------------------------------------------------------------- fused exp(QK^T) @ V'
// 128 q/block, t-step 128. Waves split 2x2 over (t-half, s-half); Q fragments
// hoisted to registers; PV is split-K over t-halves with cross-wave f32
// reduction at epilogue.
__global__ __launch_bounds__(256, 2) void k_attnpv(
    const short* __restrict__ Qb, const short* __restrict__ Kb,
    const short* __restrict__ Vt, short* __restrict__ catg) {
  __shared__ __align__(16) short Qs[128*64];
  __shared__ __align__(16) short Ks[128*64];
  __shared__ __align__(16) short Vs[64*128];
  __shared__ __align__(16) short Ps[128*128];   // 32 KB; reused as f32 scratch
  const int tid = threadIdx.x, wave = tid >> 6, lane = tid & 63;
  const int l15 = lane & 15, quad = lane >> 4;
  const int s0 = blockIdx.x * 128;
  const int bh = blockIdx.y, b = bh >> 4, h = bh & 15;
  const short* Qg  = Qb + (size_t)bh * SS * DK;
  const short* Kg  = Kb + (size_t)bh * SS * DK;
  const short* Vtg = Vt + (size_t)bh * DK * SS;
  const int th_ = wave & 1, sh = wave >> 1;     // t-half / s-half of this wave
  stage<8,128>(Qg + (size_t)s0*DK, DK, Qs, wave, lane);
  __syncthreads();
  bf16x8 qf[2][4];                              // loop-invariant Q fragments
#pragma unroll
  for (int ks = 0; ks < 2; ks++)
#pragma unroll
    for (int nf = 0; nf < 4; nf++)
      qf[ks][nf] = *(const bf16x8*)&Qs[soff<8>(sh*64 + nf*16 + l15, ks*4 + quad)];
  f32x4 out[4][4] = {};
  for (int t0 = 0; t0 < SS; t0 += 128) {
    stage<8,128>(Kg + (size_t)t0*DK, DK, Ks, wave, lane);
    stage<16,64>(Vtg + t0, SS, Vs, wave, lane);
    __syncthreads();
    // S^T quarter [64 t][64 s]: A = K rows, B = hoisted Q frags
    f32x4 sacc[4][4] = {};
#pragma unroll
    for (int ks = 0; ks < 2; ks++) {
      bf16x8 a[4];
#pragma unroll
      for (int g = 0; g < 4; g++)
        a[g] = *(const bf16x8*)&Ks[soff<8>(th_*64 + g*16 + l15, ks*4 + quad)];
#pragma unroll
      for (int g = 0; g < 4; g++)
#pragma unroll
        for (int nf = 0; nf < 4; nf++)
          sacc[g][nf] = MFMA16(a[g], qf[ks][nf], sacc[g][nf], 0, 0, 0);
    }
    // exp + pack: 4 consecutive t at fixed s -> b64 writes into Ps[s][t]
#pragma unroll
    for (int g = 0; g < 4; g++)
#pragma unroll
      for (int nf = 0; nf < 4; nf++) {
        int s_loc = sh*64 + nf*16 + l15;
        int ct = th_*8 + g*2 + (quad >> 1);
        short4v p4;
        p4[0] = f2bf(__expf(sacc[g][nf][0]));
        p4[1] = f2bf(__expf(sacc[g][nf][1]));
        p4[2] = f2bf(__expf(sacc[g][nf][2]));
        p4[3] = f2bf(__expf(sacc[g][nf][3]));
        *(short4v*)&Ps[s_loc*128 + ((ct ^ (s_loc & 15)) << 3) + ((quad & 1) << 2)] = p4;
      }
    __syncthreads();
    // out[s][dk] += P[s-half][t-half] @ V'[t-half][dk]
#pragma unroll
    for (int ks = 0; ks < 2; ks++) {
      bf16x8 pa[4], vb[4];
#pragma unroll
      for (int g = 0; g < 4; g++) {
        int s_loc = sh*64 + g*16 + l15;
        int ct2 = th_*8 + ks*4 + quad;
        pa[g] = *(const bf16x8*)&Ps[s_loc*128 + ((ct2 ^ (s_loc & 15)) << 3)];
      }
#pragma unroll
      for (int nf = 0; nf < 4; nf++)
        vb[nf] = *(const bf16x8*)&Vs[soff<16>(nf*16 + l15, th_*8 + ks*4 + quad)];
#pragma unroll
      for (int g = 0; g < 4; g++)
#pragma unroll
        for (int nf = 0; nf < 4; nf++)
          out[g][nf] = MFMA16(pa[g], vb[nf], out[g][nf], 0, 0, 0);
    }
    __syncthreads();
  }
  // cross-wave reduce over t-halves, then store
  float* Pf = (float*)Ps;                       // [2][64][64]
  if (th_) {
#pragma unroll
    for (int g = 0; g < 4; g++)
#pragma unroll
      for (int nf = 0; nf < 4; nf++)
#pragma unroll
        for (int r = 0; r < 4; r++)
          Pf[sh*4096 + (g*16 + quad*4 + r)*64 + nf*16 + l15] = out[g][nf][r];
  }
  __syncthreads();
  if (!th_) {
#pragma unroll
    for (int g = 0; g < 4; g++)
#pragma unroll
      for (int nf = 0; nf < 4; nf++)
#pragma unroll
        for (int r = 0; r < 4; r++) {
          float v = out[g][nf][r] + Pf[sh*4096 + (g*16 + quad*4 + r)*64 + nf*16 + l15];
          int s = s0 + sh*64 + g*16 + quad*4 + r;
          catg[(size_t)(b*SS + s)*DM + h*DK + nf*16 + l15] = f2bf(v);
        }
  }
}

// ---------------------------------------------------------------- output proj
__global__ __launch_bounds__(256) void k_final(
    const short* __restrict__ catg, const short* __restrict__ Wct,
    const float* __restrict__ bc, float* __restrict__ out) {
  __shared__ __align__(16) short As[128*64];
  __shared__ __align__(16) short Bs[128*64];
  const int tid = threadIdx.x, wave = tid >> 6, lane = tid & 63;
  const int l15 = lane & 15, quad = lane >> 4;
  const int m0 = blockIdx.x * 128, n0 = blockIdx.y * 128;
  const int mw = (wave & 1) * 64, nw = (wave >> 1) * 64;
  f32x4 acc[4][4] = {};
  for (int k0 = 0; k0 < DM; k0 += 64) {
    stage<8,128>(catg + (size_t)m0*DM + k0, DM, As, wave, lane);
    stage<8,128>(Wct  + (size_t)n0*DM + k0, DM, Bs, wave, lane);
    __syncthreads();
#pragma unroll
    for (int ks = 0; ks < 2; ks++) {
      bf16x8 a[4], b[4];
#pragma unroll
      for (int g = 0; g < 4; g++)  a[g]  = *(const bf16x8*)&As[soff<8>(mw + g*16 + l15,  ks*4 + quad)];
#pragma unroll
      for (int nf = 0; nf < 4; nf++) b[nf] = *(const bf16x8*)&Bs[soff<8>(nw + nf*16 + l15, ks*4 + quad)];
#pragma unroll
      for (int g = 0; g < 4; g++)
#pragma unroll
        for (int nf = 0; nf < 4; nf++)
          acc[g][nf] = MFMA16(a[g], b[nf], acc[g][nf], 0, 0, 0);
    }
    __syncthreads();
  }
#pragma unroll
  for (int nf = 0; nf < 4; nf++) {
    int n = n0 + nw + nf*16 + l15;
    float bval = bc[n];
#pragma unroll
    for (int g = 0; g < 4; g++)
#pragma unroll
      for (int r = 0; r < 4; r++) {
        int m = m0 + mw + g*16 + quad*4 + r;
        out[(size_t)m*DM + n] = acc[g][nf][r] + bval;
      }
  }
}

extern "C" void kernel_launch(void* const* d_in, const int* in_sizes, int n_in,
                              void* d_out, int out_size, void* d_ws, size_t ws_size,
                              hipStream_t stream) {
  (void)in_sizes; (void)n_in; (void)out_size; (void)ws_size;
  const float* x  = (const float*)d_in[0];
  const float* Wq = (const float*)d_in[1];
  const float* bq = (const float*)d_in[2];
  const float* Wk = (const float*)d_in[3];
  const float* bk = (const float*)d_in[4];
  const float* Wv = (const float*)d_in[5];
  const float* bv = (const float*)d_in[6];
  const float* Wc = (const float*)d_in[7];
  const float* bc = (const float*)d_in[8];
  float* out = (float*)d_out;

  char* ws = (char*)d_ws;
  size_t o = 0;
  short* xb  = (short*)(ws + o); o += (size_t)BS*DM*2;
  short* Wt  = (short*)(ws + o); o += (size_t)3*NH*DK*DM*2;
  short* Wct = (short*)(ws + o); o += (size_t)DM*DM*2;
  short* Qb  = (short*)(ws + o); o += (size_t)BB*NH*SS*DK*2;
  short* Kb  = (short*)(ws + o); o += (size_t)BB*NH*SS*DK*2;
  short* Vb  = (short*)(ws + o); o += (size_t)BB*NH*SS*DK*2;
  short* Vt  = (short*)(ws + o); o += (size_t)BB*NH*DK*SS*2;
  short* cat = (short*)(ws + o); o += (size_t)BS*DM*2;

  const int nconv = BS*DM/(256*4) + 48*16 + 256;   // 5120 blocks
  k_convert<<<dim3(nconv), 256, 0, stream>>>(x, Wq, Wk, Wv, Wc, xb, Wt, Wct);
  k_qkv   <<<dim3(BS/128, 3*NH*DK/128), 256, 0, stream>>>(xb, Wt, bq, bk, bv, Qb, Kb, Vb);
  k_stats <<<dim3(SS/128, BB*NH),       256, 0, stream>>>(Qb, Kb, Vb, Vt);
  k_attnpv<<<dim3(SS/128, BB*NH),       256, 0, stream>>>(Qb, Kb, Vt, cat);
  k_final <<<dim3(BS/128, DM/128),      256, 0, stream>>>(cat, Wct, bc, out);
}

// Round 5
// 225.659 us; speedup vs baseline: 1.3143x; 1.0611x over previous
//
#include <hip/hip_runtime.h>
#include <hip/hip_bf16.h>

#define NH 16
#define DK 64
#define DM 1024
#define BB 2
#define SS 2048
#define BS (BB*SS)   // 4096 rows of x

typedef __attribute__((ext_vector_type(8))) short bf16x8;
typedef __attribute__((ext_vector_type(4))) short short4v;
typedef __attribute__((ext_vector_type(4))) float f32x4;

#define MFMA16 __builtin_amdgcn_mfma_f32_16x16x32_bf16

static __device__ __forceinline__ float bf2f(short s) {
  union { unsigned u; float f; } v;
  v.u = ((unsigned)(unsigned short)s) << 16;
  return v.f;
}
static __device__ __forceinline__ short f2bf(float f) {
  union { float f; unsigned u; } v; v.f = f;
  unsigned r = (v.u + 0x7fffu + ((v.u >> 16) & 1u)) >> 16;  // RTNE
  return (short)r;
}
// packed RTNE f32x2 -> bf16x2 (v_cvt_pk_bf16_f32 on gfx950)
static __device__ __forceinline__ unsigned pkbf(float a, float b) {
  __hip_bfloat162 h = __float22bfloat162_rn(make_float2(a, b));
  union { __hip_bfloat162 h; unsigned u; } c; c.h = h; return c.u;
}

// Swizzled LDS tile: rows of C16*16 bytes, 16B chunk index XORed with row.
template<int C16>
static __device__ __forceinline__ int soff(int row, int chunk) {
  return row*(C16*8) + ((chunk ^ (row & (C16-1))) << 3);
}

// Async global->LDS staging, 16B/lane, swizzle folded into the global address.
template<int C16, int R>
static __device__ __forceinline__ void stage(const short* __restrict__ g, int gstride,
                                             short* l, int wave, int lane) {
  const int rloc = lane / C16;
  const int c    = lane % C16;
#pragma unroll
  for (int rr = 0; rr < R; rr += 4*(64/C16)) {
    int rbase = rr + wave*(64/C16);          // wave-uniform
    int row   = rbase + rloc;
    int cg    = c ^ (row & (C16-1));
    __builtin_amdgcn_global_load_lds(
        (const __attribute__((address_space(1))) void*)(g + (size_t)row*gstride + cg*8),
        (__attribute__((address_space(3))) void*)(l + rbase*(C16*8)),
        16, 0, 0);
  }
}

// ---------------------------------------------------------------- convert
__global__ __launch_bounds__(256) void k_convert(
    const float* __restrict__ x,
    const float* __restrict__ Wq, const float* __restrict__ Wk,
    const float* __restrict__ Wv, const float* __restrict__ Wc,
    short* __restrict__ xb, short* __restrict__ Wt, short* __restrict__ Wct) {
  __shared__ float T[64][65];
  const int tid = threadIdx.x;
  int bx = blockIdx.x;
  const int XB = BS*DM/(256*4);                 // 4096 blocks: x -> xb
  if (bx < XB) {
    int i = (bx*256 + tid)*4;
    float4 v = *(const float4*)&x[i];
    union { unsigned u[2]; short4v s; } o;
    o.u[0] = pkbf(v.x, v.y); o.u[1] = pkbf(v.z, v.w);
    *(short4v*)&xb[i] = o.s;
    return;
  }
  bx -= XB;
  if (bx < 48*16) {                             // Wq/Wk/Wv -> Wt[th][dk][d]
    int th = bx >> 4, d0 = (bx & 15) * 64;
    int type = th >> 4, h = th & 15;
    const float* W = ((type == 0) ? Wq : (type == 1) ? Wk : Wv)
                     + (size_t)h*DM*DK + (size_t)d0*DK;
#pragma unroll
    for (int p = 0; p < 4; p++) {
      int dr = p*16 + (tid >> 4), dkc = (tid & 15) * 4;
      float4 v = *(const float4*)&W[(size_t)dr*DK + dkc];
      T[dkc+0][dr]=v.x; T[dkc+1][dr]=v.y; T[dkc+2][dr]=v.z; T[dkc+3][dr]=v.w;
    }
    __syncthreads();
#pragma unroll
    for (int e = 0; e < 2; e++) {
      int c = tid*2 + e, dk = c >> 3, dd = (c & 7) * 8;
      union { short s[8]; int4 v; } u;
#pragma unroll
      for (int j = 0; j < 8; j++) u.s[j] = f2bf(T[dk][dd+j]);
      *(int4*)&Wt[((size_t)th*DK + dk)*DM + d0 + dd] = u.v;
    }
    return;
  }
  bx -= 48*16;                                  // Wc -> Wct[n][k]
  int n0 = (bx >> 4) * 64, k0 = (bx & 15) * 64;
#pragma unroll
  for (int p = 0; p < 4; p++) {
    int kr = p*16 + (tid >> 4), nc = (tid & 15) * 4;
    float4 v = *(const float4*)&Wc[(size_t)(k0+kr)*DM + n0 + nc];
    T[nc+0][kr]=v.x; T[nc+1][kr]=v.y; T[nc+2][kr]=v.z; T[nc+3][kr]=v.w;
  }
  __syncthreads();
#pragma unroll
  for (int e = 0; e < 2; e++) {
    int c = tid*2 + e, n = c >> 3, kk = (c & 7) * 8;
    union { short s[8]; int4 v; } u;
#pragma unroll
    for (int j = 0; j < 8; j++) u.s[j] = f2bf(T[n][kk+j]);
    *(int4*)&Wct[(size_t)(n0+n)*DM + k0 + kk] = u.v;
  }
}

// ---------------------------------------------------------------- QKV GEMM
// XCD-swizzled 1-D grid: each XCD owns 4 m-tiles (xb slice L2-resident).
__global__ __launch_bounds__(256) void k_qkv(
    const short* __restrict__ xb, const short* __restrict__ Wt,
    const float* __restrict__ bq, const float* __restrict__ bk,
    const float* __restrict__ bv,
    short* __restrict__ Qb, short* __restrict__ Kb, short* __restrict__ Vb) {
  __shared__ __align__(16) short As[128*64];
  __shared__ __align__(16) short Bs[128*64];
  const int tid = threadIdx.x, wave = tid >> 6, lane = tid & 63;
  const int l15 = lane & 15, quad = lane >> 4;
  const int id = blockIdx.x, xcd = id & 7, j = id >> 3;
  const int m0 = (xcd*4 + (j & 3)) * 128, n0 = (j >> 2) * 128;
  const int mw = (wave & 1) * 64, nw = (wave >> 1) * 64;
  f32x4 acc[4][4] = {};
  for (int k0 = 0; k0 < DM; k0 += 64) {
    stage<8,128>(xb + (size_t)m0*DM + k0, DM, As, wave, lane);
    stage<8,128>(Wt + (size_t)n0*DM + k0, DM, Bs, wave, lane);
    __syncthreads();
#pragma unroll
    for (int ks = 0; ks < 2; ks++) {
      bf16x8 a[4], b[4];
#pragma unroll
      for (int g = 0; g < 4; g++)  a[g]  = *(const bf16x8*)&As[soff<8>(mw + g*16 + l15,  ks*4 + quad)];
#pragma unroll
      for (int nf = 0; nf < 4; nf++) b[nf] = *(const bf16x8*)&Bs[soff<8>(nw + nf*16 + l15, ks*4 + quad)];
#pragma unroll
      for (int g = 0; g < 4; g++)
#pragma unroll
        for (int nf = 0; nf < 4; nf++)
          acc[g][nf] = MFMA16(a[g], b[nf], acc[g][nf], 0, 0, 0);
    }
    __syncthreads();
  }
  const int th = (n0 + nw) >> 6;
  const int type = th >> 4, h = th & 15;
  short* dst = (type == 0) ? Qb : (type == 1) ? Kb : Vb;
  const float* bias = ((type == 0) ? bq : (type == 1) ? bk : bv) + h*DK;
  const float scale = (type == 0) ? 0.125f : 1.0f;
#pragma unroll
  for (int nf = 0; nf < 4; nf++) {
    int dk = nf*16 + l15;
    float bval = bias[dk];
#pragma unroll
    for (int g = 0; g < 4; g++)
#pragma unroll
      for (int r = 0; r < 4; r++) {
        int m = m0 + mw + g*16 + quad*4 + r;
        int b_ = m >> 11, s = m & (SS-1);
        dst[(size_t)((b_*NH + h)*SS + s)*DK + dk] = f2bf((acc[g][nf][r] + bval) * scale);
      }
  }
}

// ---------------------------------------------------------------- column stats
// Q double-buffered, 1 barrier/iter, stage overlaps QK. XCD owns 4 bh.
__global__ __launch_bounds__(256) void k_stats(
    const short* __restrict__ Qb, const short* __restrict__ Kb,
    const short* __restrict__ Vb, short* __restrict__ Vt) {
  __shared__ __align__(16) short smem[3*8192];   // Ks | Qs0 | Qs1 (48 KB)
  __shared__ float red[4][64];
  __shared__ float zinv[128];
  short* Ks = smem;
  const int tid = threadIdx.x, wave = tid >> 6, lane = tid & 63;
  const int l15 = lane & 15, quad = lane >> 4;
  const int id = blockIdx.x, xcd = id & 7, j = id >> 3;
  const int bh = xcd*4 + (j & 3), t0 = (j >> 2) * 128;
  const short* Qg = Qb + (size_t)bh * SS * DK;
  const short* Kg = Kb + (size_t)bh * SS * DK;
  const int mw = (wave & 1) * 64, nw = (wave >> 1) * 64;
  stage<8,128>(Kg + (size_t)t0*DK, DK, Ks, wave, lane);
  stage<8,128>(Qg, DK, smem + 8192, wave, lane);
  __syncthreads();
  bf16x8 kf[2][4];                              // K-tile loop-invariant: hoist
#pragma unroll
  for (int ks = 0; ks < 2; ks++)
#pragma unroll
    for (int nf = 0; nf < 4; nf++)
      kf[ks][nf] = *(const bf16x8*)&Ks[soff<8>(nw + nf*16 + l15, ks*4 + quad)];
  float csum[4] = {0.f, 0.f, 0.f, 0.f};
  for (int it = 0; it < SS/128; it++) {
    if (it + 1 < SS/128)
      stage<8,128>(Qg + (size_t)(it+1)*128*DK, DK,
                   smem + 8192 + (((it+1) & 1) << 13), wave, lane);
    const short* Qs = smem + 8192 + ((it & 1) << 13);
    f32x4 acc[4][4] = {};
#pragma unroll
    for (int ks = 0; ks < 2; ks++) {
      bf16x8 a[4];
#pragma unroll
      for (int g = 0; g < 4; g++) a[g] = *(const bf16x8*)&Qs[soff<8>(mw + g*16 + l15, ks*4 + quad)];
#pragma unroll
      for (int g = 0; g < 4; g++)
#pragma unroll
        for (int nf = 0; nf < 4; nf++)
          acc[g][nf] = MFMA16(a[g], kf[ks][nf], acc[g][nf], 0, 0, 0);
    }
#pragma unroll
    for (int nf = 0; nf < 4; nf++)
#pragma unroll
      for (int g = 0; g < 4; g++)
#pragma unroll
        for (int r = 0; r < 4; r++)
          csum[nf] += __expf(acc[g][nf][r]);
    __syncthreads();   // drains next-Q stage; Qs[cur] free for it+2
  }
#pragma unroll
  for (int nf = 0; nf < 4; nf++) {
    csum[nf] += __shfl_xor(csum[nf], 16, 64);
    csum[nf] += __shfl_xor(csum[nf], 32, 64);
  }
  if (lane < 16) {
#pragma unroll
    for (int nf = 0; nf < 4; nf++) red[wave][nf*16 + lane] = csum[nf];
  }
  __syncthreads();
  if (tid < 128) {
    int half = tid >> 6, c = tid & 63;
    zinv[tid] = 1.0f / (red[half*2][c] + red[half*2 + 1][c]);
  }
  __syncthreads();
  short* Vtile = smem + 8192;                   // 64x128 transposed tile
  const short* Vg = Vb + (size_t)bh * SS * DK;
#pragma unroll
  for (int it = 0; it < 4; it++) {
    int c = tid + it*256;
    int trow = c >> 3, c8 = (c & 7) * 8;
    union { int4 v; short s[8]; } u;
    u.v = *(const int4*)&Vg[(size_t)(t0 + trow)*DK + c8];
    float sc = zinv[trow];
#pragma unroll
    for (int jj = 0; jj < 8; jj++) {
      int dk = c8 + jj;
      Vtile[dk*128 + (((trow >> 3) ^ (dk & 15)) << 3) + (trow & 7)] = f2bf(bf2f(u.s[jj]) * sc);
    }
  }
  __syncthreads();
  short* Vtg = Vt + (size_t)bh * DK * SS;
#pragma unroll
  for (int it = 0; it < 4; it++) {
    int row = it*16 + (tid >> 4), cc = tid & 15;
    *(int4*)&Vtg[(size_t)row*SS + t0 + cc*8] = *(const int4*)&Vtile[soff<16>(row, cc)];
  }
}

// ---------------------------------------------------------------- fused exp(QK^T) @ V'
// 2 barriers/iter; K/V staging for iter i+1 overlaps PV_i; Vs double-buffered;
// Ps aliases dead Qs region (Q hoisted to registers). LDS 80 KB, 2 blocks/CU.
__global__ __launch_bounds__(256, 2) void k_attnpv(
    const short* __restrict__ Qb, const short* __restrict__ Kb,
    const short* __restrict__ Vt, short* __restrict__ catg) {
  __shared__ __align__(16) short smem[40960];   // Ps(32K, aliases Qs) | Ks | Vs0 | Vs1
  short* Qs = smem;                 // 128x64, dead after hoist
  short* Ps = smem;                 // 128x128
  short* Ks = smem + 16384;         // 128x64
  const int tid = threadIdx.x, wave = tid >> 6, lane = tid & 63;
  const int l15 = lane & 15, quad = lane >> 4;
  const int id = blockIdx.x, xcd = id & 7, jj = id >> 3;
  const int bh = xcd*4 + (jj & 3), s0 = (jj >> 2) * 128;
  const int b = bh >> 4, h = bh & 15;
  const short* Qg  = Qb + (size_t)bh * SS * DK;
  const short* Kg  = Kb + (size_t)bh * SS * DK;
  const short* Vtg = Vt + (size_t)bh * DK * SS;
  const int th_ = wave & 1, sh = wave >> 1;     // t-half / s-half of this wave
  stage<8,128>(Qg + (size_t)s0*DK, DK, Qs, wave, lane);
  stage<8,128>(Kg, DK, Ks, wave, lane);
  stage<16,64>(Vtg, SS, smem + 24576, wave, lane);
  __syncthreads();
  bf16x8 qf[2][4];                              // loop-invariant Q fragments
#pragma unroll
  for (int ks = 0; ks < 2; ks++)
#pragma unroll
    for (int nf = 0; nf < 4; nf++)
      qf[ks][nf] = *(const bf16x8*)&Qs[soff<8>(sh*64 + nf*16 + l15, ks*4 + quad)];
  __syncthreads();                              // all hoists done before Ps writes
  f32x4 out[4][4] = {};
  for (int it = 0; it < SS/128; it++) {
    // S^T quarter [64 t][64 s]: A = K rows, B = hoisted Q frags
    f32x4 sacc[4][4] = {};
#pragma unroll
    for (int ks = 0; ks < 2; ks++) {
      bf16x8 a[4];
#pragma unroll
      for (int g = 0; g < 4; g++)
        a[g] = *(const bf16x8*)&Ks[soff<8>(th_*64 + g*16 + l15, ks*4 + quad)];
#pragma unroll
      for (int g = 0; g < 4; g++)
#pragma unroll
        for (int nf = 0; nf < 4; nf++)
          sacc[g][nf] = MFMA16(a[g], qf[ks][nf], sacc[g][nf], 0, 0, 0);
    }
    // exp + packed cvt: 4 consecutive t at fixed s -> b64 writes into Ps[s][t]
#pragma unroll
    for (int g = 0; g < 4; g++)
#pragma unroll
      for (int nf = 0; nf < 4; nf++) {
        int s_loc = sh*64 + nf*16 + l15;
        int ct = th_*8 + g*2 + (quad >> 1);
        uint2 p;
        p.x = pkbf(__expf(sacc[g][nf][0]), __expf(sacc[g][nf][1]));
        p.y = pkbf(__expf(sacc[g][nf][2]), __expf(sacc[g][nf][3]));
        *(uint2*)&Ps[s_loc*128 + ((ct ^ (s_loc & 15)) << 3) + ((quad & 1) << 2)] = p;
      }
    __syncthreads();                            // Ps ready; Ks consumed
    if (it + 1 < SS/128) {                      // stage next K/V, overlapped w/ PV
      stage<8,128>(Kg + (size_t)(it+1)*128*DK, DK, Ks, wave, lane);
      stage<16,64>(Vtg + (it+1)*128, SS, smem + 24576 + (((it+1) & 1) << 13), wave, lane);
    }
    const short* Vs = smem + 24576 + ((it & 1) << 13);
    // out[s][dk] += P[s-half][t-half] @ V'[t-half][dk]
#pragma unroll
    for (int ks = 0; ks < 2; ks++) {
      bf16x8 pa[4], vb[4];
#pragma unroll
      for (int g = 0; g < 4; g++) {
        int s_loc = sh*64 + g*16 + l15;
        int ct2 = th_*8 + ks*4 + quad;
        pa[g] = *(const bf16x8*)&Ps[s_loc*128 + ((ct2 ^ (s_loc & 15)) << 3)];
      }
#pragma unroll
      for (int nf = 0; nf < 4; nf++)
        vb[nf] = *(const bf16x8*)&Vs[soff<16>(nf*16 + l15, th_*8 + ks*4 + quad)];
#pragma unroll
      for (int g = 0; g < 4; g++)
#pragma unroll
        for (int nf = 0; nf < 4; nf++)
          out[g][nf] = MFMA16(pa[g], vb[nf], out[g][nf], 0, 0, 0);
    }
    __syncthreads();                            // drains stages; Ps consumed
  }
  // cross-wave reduce over t-halves, then store
  float* Pf = (float*)smem;                     // [2][64][64] f32 = 32 KB
  if (th_) {
#pragma unroll
    for (int g = 0; g < 4; g++)
#pragma unroll
      for (int nf = 0; nf < 4; nf++)
#pragma unroll
        for (int r = 0; r < 4; r++)
          Pf[sh*4096 + (g*16 + quad*4 + r)*64 + nf*16 + l15] = out[g][nf][r];
  }
  __syncthreads();
  if (!th_) {
#pragma unroll
    for (int g = 0; g < 4; g++)
#pragma unroll
      for (int nf = 0; nf < 4; nf++)
#pragma unroll
        for (int r = 0; r < 4; r++) {
          float v = out[g][nf][r] + Pf[sh*4096 + (g*16 + quad*4 + r)*64 + nf*16 + l15];
          int s = s0 + sh*64 + g*16 + quad*4 + r;
          catg[(size_t)(b*SS + s)*DM + h*DK + nf*16 + l15] = f2bf(v);
        }
  }
}

// ---------------------------------------------------------------- output proj
__global__ __launch_bounds__(256) void k_final(
    const short* __restrict__ catg, const short* __restrict__ Wct,
    const float* __restrict__ bc, float* __restrict__ out) {
  __shared__ __align__(16) short As[128*64];
  __shared__ __align__(16) short Bs[128*64];
  const int tid = threadIdx.x, wave = tid >> 6, lane = tid & 63;
  const int l15 = lane & 15, quad = lane >> 4;
  const int id = blockIdx.x, xcd = id & 7, j = id >> 3;
  const int m0 = (xcd*4 + (j & 3)) * 128, n0 = (j >> 2) * 128;
  const int mw = (wave & 1) * 64, nw = (wave >> 1) * 64;
  f32x4 acc[4][4] = {};
  for (int k0 = 0; k0 < DM; k0 += 64) {
    stage<8,128>(catg + (size_t)m0*DM + k0, DM, As, wave, lane);
    stage<8,128>(Wct  + (size_t)n0*DM + k0, DM, Bs, wave, lane);
    __syncthreads();
#pragma unroll
    for (int ks = 0; ks < 2; ks++) {
      bf16x8 a[4], b[4];
#pragma unroll
      for (int g = 0; g < 4; g++)  a[g]  = *(const bf16x8*)&As[soff<8>(mw + g*16 + l15,  ks*4 + quad)];
#pragma unroll
      for (int nf = 0; nf < 4; nf++) b[nf] = *(const bf16x8*)&Bs[soff<8>(nw + nf*16 + l15, ks*4 + quad)];
#pragma unroll
      for (int g = 0; g < 4; g++)
#pragma unroll
        for (int nf = 0; nf < 4; nf++)
          acc[g][nf] = MFMA16(a[g], b[nf], acc[g][nf], 0, 0, 0);
    }
    __syncthreads();
  }
#pragma unroll
  for (int nf = 0; nf < 4; nf++) {
    int n = n0 + nw + nf*16 + l15;
    float bval = bc[n];
#pragma unroll
    for (int g = 0; g < 4; g++)
#pragma unroll
      for (int r = 0; r < 4; r++) {
        int m = m0 + mw + g*16 + quad*4 + r;
        out[(size_t)m*DM + n] = acc[g][nf][r] + bval;
      }
  }
}

extern "C" void kernel_launch(void* const* d_in, const int* in_sizes, int n_in,
                              void* d_out, int out_size, void* d_ws, size_t ws_size,
                              hipStream_t stream) {
  (void)in_sizes; (void)n_in; (void)out_size; (void)ws_size;
  const float* x  = (const float*)d_in[0];
  const float* Wq = (const float*)d_in[1];
  const float* bq = (const float*)d_in[2];
  const float* Wk = (const float*)d_in[3];
  const float* bk = (const float*)d_in[4];
  const float* Wv = (const float*)d_in[5];
  const float* bv = (const float*)d_in[6];
  const float* Wc = (const float*)d_in[7];
  const float* bc = (const float*)d_in[8];
  float* out = (float*)d_out;

  char* ws = (char*)d_ws;
  size_t o = 0;
  short* xb  = (short*)(ws + o); o += (size_t)BS*DM*2;
  short* Wt  = (short*)(ws + o); o += (size_t)3*NH*DK*DM*2;
  short* Wct = (short*)(ws + o); o += (size_t)DM*DM*2;
  short* Qb  = (short*)(ws + o); o += (size_t)BB*NH*SS*DK*2;
  short* Kb  = (short*)(ws + o); o += (size_t)BB*NH*SS*DK*2;
  short* Vb  = (short*)(ws + o); o += (size_t)BB*NH*SS*DK*2;
  short* Vt  = (short*)(ws + o); o += (size_t)BB*NH*DK*SS*2;
  short* cat = (short*)(ws + o); o += (size_t)BS*DM*2;

  const int nconv = BS*DM/(256*4) + 48*16 + 256;   // 5120 blocks
  k_convert<<<dim3(nconv), 256, 0, stream>>>(x, Wq, Wk, Wv, Wc, xb, Wt, Wct);
  k_qkv   <<<dim3(768), 256, 0, stream>>>(xb, Wt, bq, bk, bv, Qb, Kb, Vb);
  k_stats <<<dim3(512), 256, 0, stream>>>(Qb, Kb, Vb, Vt);
  k_attnpv<<<dim3(512), 256, 0, stream>>>(Qb, Kb, Vt, cat);
  k_final <<<dim3(256), 256, 0, stream>>>(cat, Wct, bc, out);
}

// Round 6
// 220.055 us; speedup vs baseline: 1.3477x; 1.0255x over previous
//
#include <hip/hip_runtime.h>
#include <hip/hip_bf16.h>

#define NH 16
#define DK 64
#define DM 1024
#define BB 2
#define SS 2048
#define BS (BB*SS)   // 4096 rows of x

typedef __attribute__((ext_vector_type(8))) short bf16x8;
typedef __attribute__((ext_vector_type(4))) short short4v;
typedef __attribute__((ext_vector_type(4))) float f32x4;

#define MFMA16 __builtin_amdgcn_mfma_f32_16x16x32_bf16

// K=16 MFMA: P fragments (QK C-layout) feed PV directly as A-operands.
static __device__ __forceinline__ f32x4 MFMA16K16(short4v a, short4v b, f32x4 c) {
#if __has_builtin(__builtin_amdgcn_mfma_f32_16x16x16bf16_1k)
  return __builtin_amdgcn_mfma_f32_16x16x16bf16_1k(a, b, c, 0, 0, 0);
#else
  asm volatile("v_mfma_f32_16x16x16_bf16 %0, %1, %2, %0" : "+v"(c) : "v"(a), "v"(b));
  return c;
#endif
}

// native 2^x (log2e folded into Q scale upstream)
#if __has_builtin(__builtin_amdgcn_exp2f)
#define EXP2(x) __builtin_amdgcn_exp2f(x)
#else
#define EXP2(x) __expf((x) * 0.6931471805599453f)
#endif

static __device__ __forceinline__ float bf2f(short s) {
  union { unsigned u; float f; } v;
  v.u = ((unsigned)(unsigned short)s) << 16;
  return v.f;
}
static __device__ __forceinline__ short f2bf(float f) {
  union { float f; unsigned u; } v; v.f = f;
  unsigned r = (v.u + 0x7fffu + ((v.u >> 16) & 1u)) >> 16;  // RTNE
  return (short)r;
}
// packed RTNE f32x2 -> bf16x2 (v_cvt_pk_bf16_f32 on gfx950)
static __device__ __forceinline__ unsigned pkbf(float a, float b) {
  __hip_bfloat162 h = __float22bfloat162_rn(make_float2(a, b));
  union { __hip_bfloat162 h; unsigned u; } c; c.h = h; return c.u;
}

// Swizzled LDS tile: rows of C16*16 bytes, 16B chunk index XORed with row.
template<int C16>
static __device__ __forceinline__ int soff(int row, int chunk) {
  return row*(C16*8) + ((chunk ^ (row & (C16-1))) << 3);
}

// Async global->LDS staging, 16B/lane, swizzle folded into the global address.
template<int C16, int R>
static __device__ __forceinline__ void stage(const short* __restrict__ g, int gstride,
                                             short* l, int wave, int lane) {
  const int rloc = lane / C16;
  const int c    = lane % C16;
#pragma unroll
  for (int rr = 0; rr < R; rr += 4*(64/C16)) {
    int rbase = rr + wave*(64/C16);          // wave-uniform
    int row   = rbase + rloc;
    int cg    = c ^ (row & (C16-1));
    __builtin_amdgcn_global_load_lds(
        (const __attribute__((address_space(1))) void*)(g + (size_t)row*gstride + cg*8),
        (__attribute__((address_space(3))) void*)(l + rbase*(C16*8)),
        16, 0, 0);
  }
}

// ---------------------------------------------------------------- convert
__global__ __launch_bounds__(256) void k_convert(
    const float* __restrict__ x,
    const float* __restrict__ Wq, const float* __restrict__ Wk,
    const float* __restrict__ Wv, const float* __restrict__ Wc,
    short* __restrict__ xb, short* __restrict__ Wt, short* __restrict__ Wct) {
  __shared__ float T[64][65];
  const int tid = threadIdx.x;
  int bx = blockIdx.x;
  const int XB = BS*DM/(256*4);                 // 4096 blocks: x -> xb
  if (bx < XB) {
    int i = (bx*256 + tid)*4;
    float4 v = *(const float4*)&x[i];
    union { unsigned u[2]; short4v s; } o;
    o.u[0] = pkbf(v.x, v.y); o.u[1] = pkbf(v.z, v.w);
    *(short4v*)&xb[i] = o.s;
    return;
  }
  bx -= XB;
  if (bx < 48*16) {                             // Wq/Wk/Wv -> Wt[th][dk][d]
    int th = bx >> 4, d0 = (bx & 15) * 64;
    int type = th >> 4, h = th & 15;
    const float* W = ((type == 0) ? Wq : (type == 1) ? Wk : Wv)
                     + (size_t)h*DM*DK + (size_t)d0*DK;
#pragma unroll
    for (int p = 0; p < 4; p++) {
      int dr = p*16 + (tid >> 4), dkc = (tid & 15) * 4;
      float4 v = *(const float4*)&W[(size_t)dr*DK + dkc];
      T[dkc+0][dr]=v.x; T[dkc+1][dr]=v.y; T[dkc+2][dr]=v.z; T[dkc+3][dr]=v.w;
    }
    __syncthreads();
#pragma unroll
    for (int e = 0; e < 2; e++) {
      int c = tid*2 + e, dk = c >> 3, dd = (c & 7) * 8;
      union { short s[8]; int4 v; } u;
#pragma unroll
      for (int j = 0; j < 8; j++) u.s[j] = f2bf(T[dk][dd+j]);
      *(int4*)&Wt[((size_t)th*DK + dk)*DM + d0 + dd] = u.v;
    }
    return;
  }
  bx -= 48*16;                                  // Wc -> Wct[n][k]
  int n0 = (bx >> 4) * 64, k0 = (bx & 15) * 64;
#pragma unroll
  for (int p = 0; p < 4; p++) {
    int kr = p*16 + (tid >> 4), nc = (tid & 15) * 4;
    float4 v = *(const float4*)&Wc[(size_t)(k0+kr)*DM + n0 + nc];
    T[nc+0][kr]=v.x; T[nc+1][kr]=v.y; T[nc+2][kr]=v.z; T[nc+3][kr]=v.w;
  }
  __syncthreads();
#pragma unroll
  for (int e = 0; e < 2; e++) {
    int c = tid*2 + e, n = c >> 3, kk = (c & 7) * 8;
    union { short s[8]; int4 v; } u;
#pragma unroll
    for (int j = 0; j < 8; j++) u.s[j] = f2bf(T[n][kk+j]);
    *(int4*)&Wct[(size_t)(n0+n)*DM + k0 + kk] = u.v;
  }
}

// ---------------------------------------------------------------- QKV GEMM
// XCD-swizzled 1-D grid: each XCD owns 4 m-tiles (xb slice L2-resident).
__global__ __launch_bounds__(256) void k_qkv(
    const short* __restrict__ xb, const short* __restrict__ Wt,
    const float* __restrict__ bq, const float* __restrict__ bk,
    const float* __restrict__ bv,
    short* __restrict__ Qb, short* __restrict__ Kb, short* __restrict__ Vb) {
  __shared__ __align__(16) short As[128*64];
  __shared__ __align__(16) short Bs[128*64];
  const int tid = threadIdx.x, wave = tid >> 6, lane = tid & 63;
  const int l15 = lane & 15, quad = lane >> 4;
  const int id = blockIdx.x, xcd = id & 7, j = id >> 3;
  const int m0 = (xcd*4 + (j & 3)) * 128, n0 = (j >> 2) * 128;
  const int mw = (wave & 1) * 64, nw = (wave >> 1) * 64;
  f32x4 acc[4][4] = {};
  for (int k0 = 0; k0 < DM; k0 += 64) {
    stage<8,128>(xb + (size_t)m0*DM + k0, DM, As, wave, lane);
    stage<8,128>(Wt + (size_t)n0*DM + k0, DM, Bs, wave, lane);
    __syncthreads();
#pragma unroll
    for (int ks = 0; ks < 2; ks++) {
      bf16x8 a[4], b[4];
#pragma unroll
      for (int g = 0; g < 4; g++)  a[g]  = *(const bf16x8*)&As[soff<8>(mw + g*16 + l15,  ks*4 + quad)];
#pragma unroll
      for (int nf = 0; nf < 4; nf++) b[nf] = *(const bf16x8*)&Bs[soff<8>(nw + nf*16 + l15, ks*4 + quad)];
#pragma unroll
      for (int g = 0; g < 4; g++)
#pragma unroll
        for (int nf = 0; nf < 4; nf++)
          acc[g][nf] = MFMA16(a[g], b[nf], acc[g][nf], 0, 0, 0);
    }
    __syncthreads();
  }
  const int th = (n0 + nw) >> 6;
  const int type = th >> 4, h = th & 15;
  short* dst = (type == 0) ? Qb : (type == 1) ? Kb : Vb;
  const float* bias = ((type == 0) ? bq : (type == 1) ? bk : bv) + h*DK;
  // Q gets 1/sqrt(dk) * log2(e) folded in (softmax via exp2)
  const float scale = (type == 0) ? 0.18033688011112042f : 1.0f;
#pragma unroll
  for (int nf = 0; nf < 4; nf++) {
    int dk = nf*16 + l15;
    float bval = bias[dk];
#pragma unroll
    for (int g = 0; g < 4; g++)
#pragma unroll
      for (int r = 0; r < 4; r++) {
        int m = m0 + mw + g*16 + quad*4 + r;
        int b_ = m >> 11, s = m & (SS-1);
        dst[(size_t)((b_*NH + h)*SS + s)*DK + dk] = f2bf((acc[g][nf][r] + bval) * scale);
      }
  }
}

// ---------------------------------------------------------------- column stats
// Q double-buffered, 1 barrier/iter, stage overlaps QK. XCD owns 4 bh.
__global__ __launch_bounds__(256) void k_stats(
    const short* __restrict__ Qb, const short* __restrict__ Kb,
    const short* __restrict__ Vb, short* __restrict__ Vt) {
  __shared__ __align__(16) short smem[3*8192];   // Ks | Qs0 | Qs1 (48 KB)
  __shared__ float red[4][64];
  __shared__ float zinv[128];
  short* Ks = smem;
  const int tid = threadIdx.x, wave = tid >> 6, lane = tid & 63;
  const int l15 = lane & 15, quad = lane >> 4;
  const int id = blockIdx.x, xcd = id & 7, j = id >> 3;
  const int bh = xcd*4 + (j & 3), t0 = (j >> 2) * 128;
  const short* Qg = Qb + (size_t)bh * SS * DK;
  const short* Kg = Kb + (size_t)bh * SS * DK;
  const int mw = (wave & 1) * 64, nw = (wave >> 1) * 64;
  stage<8,128>(Kg + (size_t)t0*DK, DK, Ks, wave, lane);
  stage<8,128>(Qg, DK, smem + 8192, wave, lane);
  __syncthreads();
  bf16x8 kf[2][4];                              // K-tile loop-invariant: hoist
#pragma unroll
  for (int ks = 0; ks < 2; ks++)
#pragma unroll
    for (int nf = 0; nf < 4; nf++)
      kf[ks][nf] = *(const bf16x8*)&Ks[soff<8>(nw + nf*16 + l15, ks*4 + quad)];
  float csum[4] = {0.f, 0.f, 0.f, 0.f};
  for (int it = 0; it < SS/128; it++) {
    if (it + 1 < SS/128)
      stage<8,128>(Qg + (size_t)(it+1)*128*DK, DK,
                   smem + 8192 + (((it+1) & 1) << 13), wave, lane);
    const short* Qs = smem + 8192 + ((it & 1) << 13);
    f32x4 acc[4][4] = {};
#pragma unroll
    for (int ks = 0; ks < 2; ks++) {
      bf16x8 a[4];
#pragma unroll
      for (int g = 0; g < 4; g++) a[g] = *(const bf16x8*)&Qs[soff<8>(mw + g*16 + l15, ks*4 + quad)];
#pragma unroll
      for (int g = 0; g < 4; g++)
#pragma unroll
        for (int nf = 0; nf < 4; nf++)
          acc[g][nf] = MFMA16(a[g], kf[ks][nf], acc[g][nf], 0, 0, 0);
    }
#pragma unroll
    for (int nf = 0; nf < 4; nf++)
#pragma unroll
      for (int g = 0; g < 4; g++)
#pragma unroll
        for (int r = 0; r < 4; r++)
          csum[nf] += EXP2(acc[g][nf][r]);
    __syncthreads();   // drains next-Q stage; Qs[cur] free for it+2
  }
#pragma unroll
  for (int nf = 0; nf < 4; nf++) {
    csum[nf] += __shfl_xor(csum[nf], 16, 64);
    csum[nf] += __shfl_xor(csum[nf], 32, 64);
  }
  if (lane < 16) {
#pragma unroll
    for (int nf = 0; nf < 4; nf++) red[wave][nf*16 + lane] = csum[nf];
  }
  __syncthreads();
  if (tid < 128) {
    int half = tid >> 6, c = tid & 63;
    zinv[tid] = 1.0f / (red[half*2][c] + red[half*2 + 1][c]);
  }
  __syncthreads();
  short* Vtile = smem + 8192;                   // 64x128 transposed tile
  const short* Vg = Vb + (size_t)bh * SS * DK;
#pragma unroll
  for (int it = 0; it < 4; it++) {
    int c = tid + it*256;
    int trow = c >> 3, c8 = (c & 7) * 8;
    union { int4 v; short s[8]; } u;
    u.v = *(const int4*)&Vg[(size_t)(t0 + trow)*DK + c8];
    float sc = zinv[trow];
#pragma unroll
    for (int jj = 0; jj < 8; jj++) {
      int dk = c8 + jj;
      Vtile[dk*128 + (((trow >> 3) ^ (dk & 15)) << 3) + (trow & 7)] = f2bf(bf2f(u.s[jj]) * sc);
    }
  }
  __syncthreads();
  short* Vtg = Vt + (size_t)bh * DK * SS;
#pragma unroll
  for (int it = 0; it < 4; it++) {
    int row = it*16 + (tid >> 4), cc = tid & 15;
    *(int4*)&Vtg[(size_t)row*SS + t0 + cc*8] = *(const int4*)&Vtile[soff<16>(row, cc)];
  }
}

// ---------------------------------------------------------------- fused exp2(QK^T) @ V'
// P never touches LDS: QK C-layout fragments are exactly the A-operand layout
// of v_mfma_f32_16x16x16_bf16 (m-tile=s, k-tile=t16). 1 barrier/iter; K/V
// double-buffered; staging for it+1 overlaps PV_it. LDS 64 KB, 2 blocks/CU.
__global__ __launch_bounds__(256, 2) void k_attnpv(
    const short* __restrict__ Qb, const short* __restrict__ Kb,
    const short* __restrict__ Vt, short* __restrict__ catg) {
  __shared__ __align__(16) short smem[32768];   // Ks0|Ks1|Vs0|Vs1 (16 KB each)
  const int tid = threadIdx.x, wave = tid >> 6, lane = tid & 63;
  const int l15 = lane & 15, quad = lane >> 4;
  const int id = blockIdx.x, xcd = id & 7, jj = id >> 3;
  const int bh = xcd*4 + (jj & 3), s0 = (jj >> 2) * 128;
  const int b = bh >> 4, h = bh & 15;
  const short* Qg  = Qb + (size_t)bh * SS * DK;
  const short* Kg  = Kb + (size_t)bh * SS * DK;
  const short* Vtg = Vt + (size_t)bh * DK * SS;
  const int th_ = wave & 1, sh = wave >> 1;     // t-half / s-half of this wave
  stage<8,128>(Qg + (size_t)s0*DK, DK, smem + 8192, wave, lane);  // Qs aliases Ks1
  stage<8,128>(Kg, DK, smem, wave, lane);                          // Ks0
  stage<16,64>(Vtg, SS, smem + 16384, wave, lane);                 // Vs0
  __syncthreads();
  bf16x8 qf[2][4];                              // loop-invariant Q fragments
#pragma unroll
  for (int ks = 0; ks < 2; ks++)
#pragma unroll
    for (int nf = 0; nf < 4; nf++)
      qf[ks][nf] = *(const bf16x8*)&smem[8192 + soff<8>(sh*64 + nf*16 + l15, ks*4 + quad)];
  __syncthreads();                              // hoists done before Ks1 staged
  f32x4 out[4][4] = {};
  for (int it = 0; it < SS/128; it++) {
    const short* Ks = smem + ((it & 1) << 13);
    const short* Vs = smem + 16384 + ((it & 1) << 13);
    // S^T quarter [64 t][64 s]: A = K rows, B = hoisted Q frags (K=32 MFMA)
    f32x4 sacc[4][4] = {};
#pragma unroll
    for (int ks = 0; ks < 2; ks++) {
      bf16x8 a[4];
#pragma unroll
      for (int g = 0; g < 4; g++)
        a[g] = *(const bf16x8*)&Ks[soff<8>(th_*64 + g*16 + l15, ks*4 + quad)];
#pragma unroll
      for (int g = 0; g < 4; g++)
#pragma unroll
        for (int nf = 0; nf < 4; nf++)
          sacc[g][nf] = MFMA16(a[g], qf[ks][nf], sacc[g][nf], 0, 0, 0);
    }
    // exp2 + pack in registers: tile (g,nf) C-frag == A-frag (m=nf s-tile, k=g)
    short4v pa[4][4];                           // pa[nf][g]
#pragma unroll
    for (int g = 0; g < 4; g++)
#pragma unroll
      for (int nf = 0; nf < 4; nf++) {
        union { unsigned u[2]; short4v s; } pu;
        pu.u[0] = pkbf(EXP2(sacc[g][nf][0]), EXP2(sacc[g][nf][1]));
        pu.u[1] = pkbf(EXP2(sacc[g][nf][2]), EXP2(sacc[g][nf][3]));
        pa[nf][g] = pu.s;
      }
    if (it + 1 < SS/128) {                      // stage next K/V over PV
      stage<8,128>(Kg + (size_t)(it+1)*128*DK, DK, smem + (((it+1) & 1) << 13), wave, lane);
      stage<16,64>(Vtg + (it+1)*128, SS, smem + 16384 + (((it+1) & 1) << 13), wave, lane);
    }
    // out[s][dk] += P @ V' via K=16 MFMA; B-frags = b64 reads of Vs
#pragma unroll
    for (int g = 0; g < 4; g++) {
      short4v vb[4];
#pragma unroll
      for (int nv = 0; nv < 4; nv++) {
        int row = nv*16 + l15;
        int ct = (8*th_ + 2*g + (quad >> 1)) ^ (row & 15);
        vb[nv] = *(const short4v*)&Vs[row*128 + (ct << 3) + ((quad & 1) << 2)];
      }
#pragma unroll
      for (int nf = 0; nf < 4; nf++)
#pragma unroll
        for (int nv = 0; nv < 4; nv++)
          out[nf][nv] = MFMA16K16(pa[nf][g], vb[nv], out[nf][nv]);
    }
    __syncthreads();                            // drains stages + Ks/Vs reads
  }
  // cross-wave reduce over t-halves, then store
  float* Pf = (float*)smem;                     // [2][64][64] f32 = 32 KB
  if (th_) {
#pragma unroll
    for (int nf = 0; nf < 4; nf++)
#pragma unroll
      for (int nv = 0; nv < 4; nv++)
#pragma unroll
        for (int r = 0; r < 4; r++)
          Pf[sh*4096 + (nf*16 + quad*4 + r)*64 + nv*16 + l15] = out[nf][nv][r];
  }
  __syncthreads();
  if (!th_) {
#pragma unroll
    for (int nf = 0; nf < 4; nf++)
#pragma unroll
      for (int nv = 0; nv < 4; nv++)
#pragma unroll
        for (int r = 0; r < 4; r++) {
          float v = out[nf][nv][r] + Pf[sh*4096 + (nf*16 + quad*4 + r)*64 + nv*16 + l15];
          int s = s0 + sh*64 + nf*16 + quad*4 + r;
          catg[(size_t)(b*SS + s)*DM + h*DK + nv*16 + l15] = f2bf(v);
        }
  }
}

// ---------------------------------------------------------------- output proj
__global__ __launch_bounds__(256) void k_final(
    const short* __restrict__ catg, const short* __restrict__ Wct,
    const float* __restrict__ bc, float* __restrict__ out) {
  __shared__ __align__(16) short As[128*64];
  __shared__ __align__(16) short Bs[128*64];
  const int tid = threadIdx.x, wave = tid >> 6, lane = tid & 63;
  const int l15 = lane & 15, quad = lane >> 4;
  const int id = blockIdx.x, xcd = id & 7, j = id >> 3;
  const int m0 = (xcd*4 + (j & 3)) * 128, n0 = (j >> 2) * 128;
  const int mw = (wave & 1) * 64, nw = (wave >> 1) * 64;
  f32x4 acc[4][4] = {};
  for (int k0 = 0; k0 < DM; k0 += 64) {
    stage<8,128>(catg + (size_t)m0*DM + k0, DM, As, wave, lane);
    stage<8,128>(Wct  + (size_t)n0*DM + k0, DM, Bs, wave, lane);
    __syncthreads();
#pragma unroll
    for (int ks = 0; ks < 2; ks++) {
      bf16x8 a[4], b[4];
#pragma unroll
      for (int g = 0; g < 4; g++)  a[g]  = *(const bf16x8*)&As[soff<8>(mw + g*16 + l15,  ks*4 + quad)];
#pragma unroll
      for (int nf = 0; nf < 4; nf++) b[nf] = *(const bf16x8*)&Bs[soff<8>(nw + nf*16 + l15, ks*4 + quad)];
#pragma unroll
      for (int g = 0; g < 4; g++)
#pragma unroll
        for (int nf = 0; nf < 4; nf++)
          acc[g][nf] = MFMA16(a[g], b[nf], acc[g][nf], 0, 0, 0);
    }
    __syncthreads();
  }
#pragma unroll
  for (int nf = 0; nf < 4; nf++) {
    int n = n0 + nw + nf*16 + l15;
    float bval = bc[n];
#pragma unroll
    for (int g = 0; g < 4; g++)
#pragma unroll
      for (int r = 0; r < 4; r++) {
        int m = m0 + mw + g*16 + quad*4 + r;
        out[(size_t)m*DM + n] = acc[g][nf][r] + bval;
      }
  }
}

extern "C" void kernel_launch(void* const* d_in, const int* in_sizes, int n_in,
                              void* d_out, int out_size, void* d_ws, size_t ws_size,
                              hipStream_t stream) {
  (void)in_sizes; (void)n_in; (void)out_size; (void)ws_size;
  const float* x  = (const float*)d_in[0];
  const float* Wq = (const float*)d_in[1];
  const float* bq = (const float*)d_in[2];
  const float* Wk = (const float*)d_in[3];
  const float* bk = (const float*)d_in[4];
  const float* Wv = (const float*)d_in[5];
  const float* bv = (const float*)d_in[6];
  const float* Wc = (const float*)d_in[7];
  const float* bc = (const float*)d_in[8];
  float* out = (float*)d_out;

  char* ws = (char*)d_ws;
  size_t o = 0;
  short* xb  = (short*)(ws + o); o += (size_t)BS*DM*2;
  short* Wt  = (short*)(ws + o); o += (size_t)3*NH*DK*DM*2;
  short* Wct = (short*)(ws + o); o += (size_t)DM*DM*2;
  short* Qb  = (short*)(ws + o); o += (size_t)BB*NH*SS*DK*2;
  short* Kb  = (short*)(ws + o); o += (size_t)BB*NH*SS*DK*2;
  short* Vb  = (short*)(ws + o); o += (size_t)BB*NH*SS*DK*2;
  short* Vt  = (short*)(ws + o); o += (size_t)BB*NH*DK*SS*2;
  short* cat = (short*)(ws + o); o += (size_t)BS*DM*2;

  const int nconv = BS*DM/(256*4) + 48*16 + 256;   // 5120 blocks
  k_convert<<<dim3(nconv), 256, 0, stream>>>(x, Wq, Wk, Wv, Wc, xb, Wt, Wct);
  k_qkv   <<<dim3(768), 256, 0, stream>>>(xb, Wt, bq, bk, bv, Qb, Kb, Vb);
  k_stats <<<dim3(512), 256, 0, stream>>>(Qb, Kb, Vb, Vt);
  k_attnpv<<<dim3(512), 256, 0, stream>>>(Qb, Kb, Vt, cat);
  k_final <<<dim3(256), 256, 0, stream>>>(cat, Wct, bc, out);
}